// Round 2
// baseline (1553.725 us; speedup 1.0000x reference)
//
#include <hip/hip_runtime.h>
#include <hip/hip_bf16.h>

constexpr int N_HE = 50000;
constexpr int E_EDGES = 1200000;
constexpr int IN_F = 200;
constexpr int HE_DIM = 512;
constexpr int E_DIM = 128;
constexpr int Q_DIM = 64;
constexpr float SCALE = 0.125f; // 1/sqrt(64)

// ---------------- compose W12 = w1_w @ w2_w, b12 = w1_b @ w2_w + w2_b ----------------
__global__ __launch_bounds__(256) void compose_w12_kernel(
    const float* __restrict__ w1w, const float* __restrict__ w1b,
    const float* __restrict__ w2w, const float* __restrict__ w2b,
    float* __restrict__ W12, float* __restrict__ b12)
{
    int idx = blockIdx.x * 256 + threadIdx.x;
    if (idx >= 201 * 128) return;
    int row = idx >> 7, col = idx & 127;
    if (row < IN_F) {
        float s = 0.f;
        for (int h = 0; h < HE_DIM; ++h)
            s = fmaf(w1w[row * HE_DIM + h], w2w[h * E_DIM + col], s);
        W12[row * E_DIM + col] = s;
    } else {
        float s = 0.f;
        for (int h = 0; h < HE_DIM; ++h)
            s = fmaf(w1b[h], w2w[h * E_DIM + col], s);
        b12[col] = s + w2b[col];
    }
}

// ---------------- node projections ----------------
__global__ __launch_bounds__(256) void node_q_kernel(
    const float* __restrict__ feat, const float* __restrict__ w5w, const float* __restrict__ w5b,
    float* __restrict__ qt, int Nt, int Dt)
{
    int idx = blockIdx.x * 256 + threadIdx.x;
    int row = idx >> 6, col = idx & 63;
    if (row >= Nt) return;
    float s = 0.f;
    for (int k = 0; k < Dt; ++k)
        s = fmaf(feat[row * Dt + k], w5w[k * Q_DIM + col], s);
    qt[row * Q_DIM + col] = s + w5b[col];
}

__global__ __launch_bounds__(256) void node_kv_kernel(
    const float* __restrict__ qt,
    const float* __restrict__ w6, const float* __restrict__ b6,
    const float* __restrict__ w7, const float* __restrict__ b7,
    float* __restrict__ k2, float* __restrict__ v2, int Nt)
{
    int idx = blockIdx.x * 256 + threadIdx.x;
    int row = idx >> 7, col = idx & 127;
    if (row >= Nt) return;
    float s1 = 0.f, s2 = 0.f;
    for (int k = 0; k < Q_DIM; ++k) {
        float q = qt[row * Q_DIM + k];
        s1 = fmaf(q, w6[k * E_DIM + col], s1);
        s2 = fmaf(q, w7[k * E_DIM + col], s2);
    }
    k2[row * E_DIM + col] = s1 + b6[col];
    v2[row * E_DIM + col] = s2 + b7[col];
}

// ---------------- tiled f32 GEMM: C = A[M,K] @ B[K,N] + bias, opt relu ----------------
template <bool RELU>
__global__ __launch_bounds__(256) void gemm_bias_kernel(
    const float* __restrict__ A, const float* __restrict__ B, const float* __restrict__ bias,
    float* __restrict__ C, int M, int N, int K)
{
    __shared__ float As[16][68];
    __shared__ float Bs[16][68];
    const int tid = threadIdx.x;
    const int tx = tid & 15, ty = tid >> 4;
    const int bm = blockIdx.x * 64, bn = blockIdx.y * 64;
    float acc[4][4] = {};
    for (int k0 = 0; k0 < K; k0 += 16) {
        {
            int m = tid >> 2;
            int kkb = (tid & 3) * 4;
            int row = bm + m;
#pragma unroll
            for (int j = 0; j < 4; ++j) {
                int k = k0 + kkb + j;
                float v = (row < M && k < K) ? A[(size_t)row * K + k] : 0.f;
                As[kkb + j][m] = v;
            }
        }
        {
#pragma unroll
            for (int j = 0; j < 4; ++j) {
                int idx = tid + j * 256;
                int kk = idx >> 6, n = idx & 63;
                int k = k0 + kk;
                float v = (k < K && (bn + n) < N) ? B[(size_t)k * N + bn + n] : 0.f;
                Bs[kk][n] = v;
            }
        }
        __syncthreads();
#pragma unroll
        for (int kk = 0; kk < 16; ++kk) {
            float4 av = *reinterpret_cast<const float4*>(&As[kk][ty * 4]);
            float4 bv = *reinterpret_cast<const float4*>(&Bs[kk][tx * 4]);
            float a0[4] = {av.x, av.y, av.z, av.w};
            float b0[4] = {bv.x, bv.y, bv.z, bv.w};
#pragma unroll
            for (int i2 = 0; i2 < 4; ++i2)
#pragma unroll
                for (int j2 = 0; j2 < 4; ++j2)
                    acc[i2][j2] = fmaf(a0[i2], b0[j2], acc[i2][j2]);
        }
        __syncthreads();
    }
#pragma unroll
    for (int i2 = 0; i2 < 4; ++i2) {
        int row = bm + ty * 4 + i2;
        if (row >= M) continue;
#pragma unroll
        for (int j2 = 0; j2 < 4; ++j2) {
            int col = bn + tx * 4 + j2;
            if (col >= N) continue;
            float v = acc[i2][j2] + bias[col];
            if (RELU) v = fmaxf(v, 0.f);
            C[(size_t)row * N + col] = v;
        }
    }
}

// ---------------- CSR build ----------------
__global__ __launch_bounds__(256) void hist_kernel(const int* __restrict__ src, int* __restrict__ cnt, int n)
{
    int i = blockIdx.x * 256 + threadIdx.x;
    if (i < n) atomicAdd(&cnt[src[i]], 1);
}

__global__ __launch_bounds__(1024) void scan_kernel(const int* __restrict__ cnt,
                                                    int* __restrict__ rows,
                                                    int* __restrict__ cursor)
{
    int g = blockIdx.x;
    const int* c = cnt + g * N_HE;
    int* r = rows + g * (N_HE + 1);
    int* cur = cursor + g * N_HE;
    __shared__ int sdata[1024];
    __shared__ int s_running;
    if (threadIdx.x == 0) s_running = 0;
    __syncthreads();
    for (int base = 0; base < N_HE; base += 1024) {
        int i = base + threadIdx.x;
        int v = (i < N_HE) ? c[i] : 0;
        sdata[threadIdx.x] = v;
        __syncthreads();
        for (int off = 1; off < 1024; off <<= 1) {
            int t = 0;
            if (threadIdx.x >= off) t = sdata[threadIdx.x - off];
            __syncthreads();
            sdata[threadIdx.x] += t;
            __syncthreads();
        }
        int incl = sdata[threadIdx.x];
        int base_off = s_running;
        if (i < N_HE) {
            int e = base_off + incl - v;
            r[i] = e;
            cur[i] = e;
        }
        __syncthreads();
        if (threadIdx.x == 1023) s_running = base_off + incl;
        __syncthreads();
    }
    if (threadIdx.x == 0) r[N_HE] = s_running;
}

__global__ __launch_bounds__(256) void scatter_kernel(const int* __restrict__ src, const int* __restrict__ dst,
                                                      int* __restrict__ cursor, int* __restrict__ ebuf, int n)
{
    int i = blockIdx.x * 256 + threadIdx.x;
    if (i < n) {
        int pos = atomicAdd(&cursor[src[i]], 1);
        ebuf[pos] = dst[i];
    }
}

// ---------------- per-hyperedge online-softmax attention ----------------
__device__ __forceinline__ void wsum2(float& a, float& b)
{
#pragma unroll
    for (int mask = 32; mask; mask >>= 1) {
        a += __shfl_xor(a, mask, 64);
        b += __shfl_xor(b, mask, 64);
    }
}

__global__ __launch_bounds__(256) void attn_kernel(
    const float* __restrict__ q_he,    // [N_HE,128]
    const float* __restrict__ k2_all,  // [1489,128]
    const float* __restrict__ v2_all,
    const int* __restrict__ rows_all,  // 3*(N_HE+1)
    const int* __restrict__ ebuf_all,  // 3*E
    float* __restrict__ he_new)        // [N_HE,384]
{
    int wid = blockIdx.x * 4 + (threadIdx.x >> 6);
    int lane = threadIdx.x & 63;
    int g = wid / N_HE;
    int h = wid - g * N_HE;
    const int toff_tab[3] = {0, 167, 1048};
    int toff = toff_tab[g];
    const float* k2 = k2_all + (size_t)toff * E_DIM;
    const float* v2 = v2_all + (size_t)toff * E_DIM;
    const int* rows = rows_all + g * (N_HE + 1);
    const int* ebuf = ebuf_all + (size_t)g * E_EDGES;

    float qa = q_he[(size_t)h * E_DIM + lane];
    float qb = q_he[(size_t)h * E_DIM + 64 + lane];
    int start = rows[h], end = rows[h + 1];

    float m = -INFINITY, denom = 0.f, acca = 0.f, accb = 0.f;
    int i = start;
    for (; i + 2 <= end; i += 2) {
        int d0 = ebuf[i], d1 = ebuf[i + 1];
        const float* k0p = k2 + (size_t)d0 * E_DIM;
        const float* k1p = k2 + (size_t)d1 * E_DIM;
        float p0 = k0p[lane] * qa + k0p[64 + lane] * qb;
        float p1 = k1p[lane] * qa + k1p[64 + lane] * qb;
        wsum2(p0, p1);
        const float* v0p = v2 + (size_t)d0 * E_DIM;
        const float* v1p = v2 + (size_t)d1 * E_DIM;
        float v0a = v0p[lane], v0b = v0p[64 + lane];
        float v1a = v1p[lane], v1b = v1p[64 + lane];
        float s0 = p0 * SCALE; s0 = s0 > 0.f ? s0 : 0.01f * s0;
        float s1 = p1 * SCALE; s1 = s1 > 0.f ? s1 : 0.01f * s1;
        float newm = fmaxf(m, fmaxf(s0, s1));
        float scale = __expf(m - newm);
        float w0 = __expf(s0 - newm), w1 = __expf(s1 - newm);
        denom = denom * scale + w0 + w1;
        acca = fmaf(acca, scale, fmaf(w0, v0a, w1 * v1a));
        accb = fmaf(accb, scale, fmaf(w0, v0b, w1 * v1b));
        m = newm;
    }
    if (i < end) {
        int d0 = ebuf[i];
        const float* k0p = k2 + (size_t)d0 * E_DIM;
        float p0 = k0p[lane] * qa + k0p[64 + lane] * qb;
        float dummy = 0.f;
        wsum2(p0, dummy);
        const float* v0p = v2 + (size_t)d0 * E_DIM;
        float v0a = v0p[lane], v0b = v0p[64 + lane];
        float s0 = p0 * SCALE; s0 = s0 > 0.f ? s0 : 0.01f * s0;
        float newm = fmaxf(m, s0);
        float scale = __expf(m - newm);
        float w0 = __expf(s0 - newm);
        denom = denom * scale + w0;
        acca = fmaf(acca, scale, w0 * v0a);
        accb = fmaf(accb, scale, w0 * v0b);
        m = newm;
    }
    float rden = 1.f / fmaxf(denom, 1e-20f);
    float* out = he_new + (size_t)h * 384 + g * E_DIM;
    out[lane] = acca * rden;
    out[64 + lane] = accb * rden;
}

// ---------------- launch ----------------
extern "C" void kernel_launch(void* const* d_in, const int* in_sizes, int n_in,
                              void* d_out, int out_size, void* d_ws, size_t ws_size,
                              hipStream_t stream)
{
    const float* he_feat = (const float*)d_in[0];
    const float* feat_g[3] = {(const float*)d_in[1], (const float*)d_in[2], (const float*)d_in[3]};
    const float* w1w = (const float*)d_in[4];
    const float* w1b = (const float*)d_in[5];
    const float* w2w = (const float*)d_in[6];
    const float* w2b = (const float*)d_in[7];
    // d_in[8..11] = w3,w4 : dead code, unused
    const float* w5w_g[3] = {(const float*)d_in[12], (const float*)d_in[14], (const float*)d_in[16]};
    const float* w5b_g[3] = {(const float*)d_in[13], (const float*)d_in[15], (const float*)d_in[17]};
    const float* w6w_g[3] = {(const float*)d_in[18], (const float*)d_in[22], (const float*)d_in[26]};
    const float* w6b_g[3] = {(const float*)d_in[19], (const float*)d_in[23], (const float*)d_in[27]};
    const float* w7w_g[3] = {(const float*)d_in[20], (const float*)d_in[24], (const float*)d_in[28]};
    const float* w7b_g[3] = {(const float*)d_in[21], (const float*)d_in[25], (const float*)d_in[29]};
    const float* mlp1w = (const float*)d_in[30];
    const float* mlp1b = (const float*)d_in[31];
    const float* mlp2w = (const float*)d_in[32];
    const float* mlp2b = (const float*)d_in[33];
    const int* src_g[3] = {(const int*)d_in[34], (const int*)d_in[36], (const int*)d_in[38]};
    const int* dst_g[3] = {(const int*)d_in[35], (const int*)d_in[37], (const int*)d_in[39]};
    float* out = (float*)d_out;

    const int Nt[3] = {167, 881, 441};
    const int toff[3] = {0, 167, 1048};

    // workspace layout with lifetime aliasing (peak 128 MB):
    //   region X = [0, 51.2MB): during phase 1 holds q_he/ebuf/misc; after attention
    //              it is reused for h1 (all phase-1 tenants are dead by then).
    //   he_new  = [51.2MB, 128MB)
    char* base = (char*)d_ws;
    size_t off = 0;
    auto alloc = [&](size_t bytes) {
        void* r = (void*)(base + off);
        off = (off + bytes + 255) & ~(size_t)255;
        return r;
    };
    float* q_he = (float*)alloc((size_t)N_HE * E_DIM * 4);      // 25.6 MB
    int* ebuf = (int*)alloc((size_t)3 * E_EDGES * 4);           // 14.4 MB
    float* W12 = (float*)alloc(IN_F * E_DIM * 4);
    float* b12 = (float*)alloc(E_DIM * 4);
    float* q_t = (float*)alloc(1489 * Q_DIM * 4);
    float* k2 = (float*)alloc(1489 * E_DIM * 4);
    float* v2 = (float*)alloc(1489 * E_DIM * 4);
    int* cnt = (int*)alloc(3 * N_HE * 4);
    int* rows = (int*)alloc(3 * (N_HE + 1) * 4);
    int* cursor = (int*)alloc(3 * N_HE * 4);
    size_t phase1_end = off;
    float* h1 = (float*)d_ws;                                    // aliases region X after attention
    size_t h1_bytes = (size_t)N_HE * 256 * 4;                    // 51.2 MB
    size_t he_new_off = ((phase1_end > h1_bytes ? phase1_end : h1_bytes) + 255) & ~(size_t)255;
    float* he_new = (float*)(base + he_new_off);                 // 76.8 MB

    hipMemsetAsync(cnt, 0, (size_t)3 * N_HE * 4, stream);

    // composed hyperedge projection weights
    compose_w12_kernel<<<101, 256, 0, stream>>>(w1w, w1b, w2w, w2b, W12, b12);

    // node projections (tiny)
    for (int g = 0; g < 3; ++g) {
        int grid_q = (Nt[g] * Q_DIM + 255) / 256;
        node_q_kernel<<<grid_q, 256, 0, stream>>>(feat_g[g], w5w_g[g], w5b_g[g],
                                                  q_t + (size_t)toff[g] * Q_DIM, Nt[g], Nt[g]);
    }
    for (int g = 0; g < 3; ++g) {
        int grid_kv = (Nt[g] * E_DIM + 255) / 256;
        node_kv_kernel<<<grid_kv, 256, 0, stream>>>(q_t + (size_t)toff[g] * Q_DIM,
                                                    w6w_g[g], w6b_g[g], w7w_g[g], w7b_g[g],
                                                    k2 + (size_t)toff[g] * E_DIM,
                                                    v2 + (size_t)toff[g] * E_DIM, Nt[g]);
    }

    // q_he = he_feat @ W12 + b12   [50000,128]
    {
        dim3 grid((N_HE + 63) / 64, E_DIM / 64);
        gemm_bias_kernel<false><<<grid, 256, 0, stream>>>(he_feat, W12, b12, q_he, N_HE, E_DIM, IN_F);
    }

    // CSR build per group
    {
        int grid_e = (E_EDGES + 255) / 256;
        for (int g = 0; g < 3; ++g)
            hist_kernel<<<grid_e, 256, 0, stream>>>(src_g[g], cnt + g * N_HE, E_EDGES);
        scan_kernel<<<3, 1024, 0, stream>>>(cnt, rows, cursor);
        for (int g = 0; g < 3; ++g)
            scatter_kernel<<<grid_e, 256, 0, stream>>>(src_g[g], dst_g[g], cursor + g * N_HE,
                                                       ebuf + (size_t)g * E_EDGES, E_EDGES);
    }

    // attention: one wave per (group, hyperedge)
    attn_kernel<<<(3 * N_HE) / 4, 256, 0, stream>>>(q_he, k2, v2, rows, ebuf, he_new);

    // MLP (h1 aliases the now-dead q_he/ebuf region)
    {
        dim3 grid1((N_HE + 63) / 64, 256 / 64);
        gemm_bias_kernel<true><<<grid1, 256, 0, stream>>>(he_new, mlp1w, mlp1b, h1, N_HE, 256, 384);
        dim3 grid2((N_HE + 63) / 64, 128 / 64);
        gemm_bias_kernel<true><<<grid2, 256, 0, stream>>>(h1, mlp2w, mlp2b, out, N_HE, 128, 256);
    }
}

// Round 3
// 1211.094 us; speedup vs baseline: 1.2829x; 1.2829x over previous
//
#include <hip/hip_runtime.h>
#include <hip/hip_bf16.h>

constexpr int N_HE = 50000;
constexpr int E_EDGES = 1200000;
constexpr int IN_F = 200;
constexpr int HE_DIM = 512;
constexpr int E_DIM = 128;
constexpr int Q_DIM = 64;
constexpr float SCALE = 0.125f; // 1/sqrt(64)
constexpr int N_NODES = 167 + 881 + 441; // 1489

struct GroupPtrs {
    const float* feat[3];
    const float* wa[3];
    const float* ba[3];
    const float* wb[3];
    const float* bb[3];
};

// ---------------- compose W12 = w1_w @ w2_w (row 200 = bias row) ----------------
// one block per output row, 256 threads: col = tid&127, kslice = tid>>7
__global__ __launch_bounds__(256) void compose_w12_kernel(
    const float* __restrict__ w1w, const float* __restrict__ w1b,
    const float* __restrict__ w2w, const float* __restrict__ w2b,
    float* __restrict__ W12, float* __restrict__ b12)
{
    int row = blockIdx.x; // 0..200
    int col = threadIdx.x & 127, ks = threadIdx.x >> 7;
    const float* a = (row < IN_F) ? (w1w + (size_t)row * HE_DIM) : w1b;
    float s = 0.f;
#pragma unroll 4
    for (int k = ks; k < HE_DIM; k += 2)
        s = fmaf(a[k], w2w[k * E_DIM + col], s);
    __shared__ float red[2][128];
    red[ks][col] = s;
    __syncthreads();
    if (ks == 0) {
        float v = red[0][col] + red[1][col];
        if (row < IN_F) W12[row * E_DIM + col] = v;
        else b12[col] = v + w2b[col];
    }
}

// ---------------- fused node q projection: one block per node row ----------------
__global__ __launch_bounds__(256) void node_q_fused_kernel(GroupPtrs P, float* __restrict__ qt)
{
    int b = blockIdx.x; // 0..1488
    int g = (b < 167) ? 0 : (b < 1048 ? 1 : 2);
    int row = b - (g == 0 ? 0 : (g == 1 ? 167 : 1048));
    int Dt = (g == 0) ? 167 : (g == 1 ? 881 : 441);
    const float* feat = P.feat[g] + (size_t)row * Dt;
    const float* w5 = P.wa[g];
    int col = threadIdx.x & 63, ks = threadIdx.x >> 6; // 4 k-slices
    float s = 0.f;
#pragma unroll 4
    for (int k = ks; k < Dt; k += 4)
        s = fmaf(feat[k], w5[k * Q_DIM + col], s);
    __shared__ float red[4][64];
    red[ks][col] = s;
    __syncthreads();
    if (ks == 0) {
        qt[(size_t)b * Q_DIM + col] =
            red[0][col] + red[1][col] + red[2][col] + red[3][col] + P.ba[g][col];
    }
}

// ---------------- fused node k2/v2 projection: one block per node row ----------------
__global__ __launch_bounds__(256) void node_kv_fused_kernel(
    GroupPtrs P, const float* __restrict__ qt,
    float* __restrict__ k2, float* __restrict__ v2)
{
    int b = blockIdx.x; // 0..1488
    int g = (b < 167) ? 0 : (b < 1048 ? 1 : 2);
    int col = threadIdx.x & 127, ks = threadIdx.x >> 7; // 2 k-slices of 32
    const float* w6 = P.wa[g];
    const float* w7 = P.wb[g];
    const float* q = qt + (size_t)b * Q_DIM;
    float s1 = 0.f, s2 = 0.f;
#pragma unroll 8
    for (int k = ks * 32; k < ks * 32 + 32; ++k) {
        float qv = q[k];
        s1 = fmaf(qv, w6[k * E_DIM + col], s1);
        s2 = fmaf(qv, w7[k * E_DIM + col], s2);
    }
    __shared__ float r1[2][128], r2[2][128];
    r1[ks][col] = s1;
    r2[ks][col] = s2;
    __syncthreads();
    if (ks == 0) {
        k2[(size_t)b * E_DIM + col] = r1[0][col] + r1[1][col] + P.ba[g][col];
        v2[(size_t)b * E_DIM + col] = r2[0][col] + r2[1][col] + P.bb[g][col];
    }
}

// ---------------- tiled f32 GEMM: C = A[M,K] @ B[K,N] + bias, opt relu ----------------
template <bool RELU>
__global__ __launch_bounds__(256) void gemm_bias_kernel(
    const float* __restrict__ A, const float* __restrict__ B, const float* __restrict__ bias,
    float* __restrict__ C, int M, int N, int K)
{
    __shared__ float As[16][68];
    __shared__ float Bs[16][68];
    const int tid = threadIdx.x;
    const int tx = tid & 15, ty = tid >> 4;
    const int bm = blockIdx.x * 64, bn = blockIdx.y * 64;
    float acc[4][4] = {};
    for (int k0 = 0; k0 < K; k0 += 16) {
        {
            int m = tid >> 2;
            int kkb = (tid & 3) * 4;
            int row = bm + m;
#pragma unroll
            for (int j = 0; j < 4; ++j) {
                int k = k0 + kkb + j;
                float v = (row < M && k < K) ? A[(size_t)row * K + k] : 0.f;
                As[kkb + j][m] = v;
            }
        }
        {
#pragma unroll
            for (int j = 0; j < 4; ++j) {
                int idx = tid + j * 256;
                int kk = idx >> 6, n = idx & 63;
                int k = k0 + kk;
                float v = (k < K && (bn + n) < N) ? B[(size_t)k * N + bn + n] : 0.f;
                Bs[kk][n] = v;
            }
        }
        __syncthreads();
#pragma unroll
        for (int kk = 0; kk < 16; ++kk) {
            float4 av = *reinterpret_cast<const float4*>(&As[kk][ty * 4]);
            float4 bv = *reinterpret_cast<const float4*>(&Bs[kk][tx * 4]);
            float a0[4] = {av.x, av.y, av.z, av.w};
            float b0[4] = {bv.x, bv.y, bv.z, bv.w};
#pragma unroll
            for (int i2 = 0; i2 < 4; ++i2)
#pragma unroll
                for (int j2 = 0; j2 < 4; ++j2)
                    acc[i2][j2] = fmaf(a0[i2], b0[j2], acc[i2][j2]);
        }
        __syncthreads();
    }
#pragma unroll
    for (int i2 = 0; i2 < 4; ++i2) {
        int row = bm + ty * 4 + i2;
        if (row >= M) continue;
#pragma unroll
        for (int j2 = 0; j2 < 4; ++j2) {
            int col = bn + tx * 4 + j2;
            if (col >= N) continue;
            float v = acc[i2][j2] + bias[col];
            if (RELU) v = fmaxf(v, 0.f);
            C[(size_t)row * N + col] = v;
        }
    }
}

// ---------------- CSR build ----------------
__global__ __launch_bounds__(256) void hist_kernel(const int* __restrict__ src, int* __restrict__ cnt, int n)
{
    int i = blockIdx.x * 256 + threadIdx.x;
    if (i < n) atomicAdd(&cnt[src[i]], 1);
}

__global__ __launch_bounds__(1024) void scan_kernel(const int* __restrict__ cnt,
                                                    int* __restrict__ rows,
                                                    int* __restrict__ cursor)
{
    int g = blockIdx.x;
    const int* c = cnt + g * N_HE;
    int* r = rows + g * (N_HE + 1);
    int* cur = cursor + g * N_HE;
    __shared__ int sdata[1024];
    __shared__ int s_running;
    if (threadIdx.x == 0) s_running = 0;
    __syncthreads();
    for (int base = 0; base < N_HE; base += 1024) {
        int i = base + threadIdx.x;
        int v = (i < N_HE) ? c[i] : 0;
        sdata[threadIdx.x] = v;
        __syncthreads();
        for (int off = 1; off < 1024; off <<= 1) {
            int t = 0;
            if (threadIdx.x >= off) t = sdata[threadIdx.x - off];
            __syncthreads();
            sdata[threadIdx.x] += t;
            __syncthreads();
        }
        int incl = sdata[threadIdx.x];
        int base_off = s_running;
        if (i < N_HE) {
            int e = base_off + incl - v;
            r[i] = e;
            cur[i] = e;
        }
        __syncthreads();
        if (threadIdx.x == 1023) s_running = base_off + incl;
        __syncthreads();
    }
    if (threadIdx.x == 0) r[N_HE] = s_running;
}

__global__ __launch_bounds__(256) void scatter_kernel(const int* __restrict__ src, const int* __restrict__ dst,
                                                      int* __restrict__ cursor, int* __restrict__ ebuf, int n)
{
    int i = blockIdx.x * 256 + threadIdx.x;
    if (i < n) {
        int pos = atomicAdd(&cursor[src[i]], 1);
        ebuf[pos] = dst[i];
    }
}

// ---------------- per-hyperedge online-softmax attention ----------------
__device__ __forceinline__ void wsum2(float& a, float& b)
{
#pragma unroll
    for (int mask = 32; mask; mask >>= 1) {
        a += __shfl_xor(a, mask, 64);
        b += __shfl_xor(b, mask, 64);
    }
}

__global__ __launch_bounds__(256) void attn_kernel(
    const float* __restrict__ q_he,    // [N_HE,128]
    const float* __restrict__ k2_all,  // [1489,128]
    const float* __restrict__ v2_all,
    const int* __restrict__ rows_all,  // 3*(N_HE+1)
    const int* __restrict__ ebuf_all,  // 3*E
    float* __restrict__ he_new)        // [N_HE,384]
{
    int wid = blockIdx.x * 4 + (threadIdx.x >> 6);
    int lane = threadIdx.x & 63;
    int g = wid / N_HE;
    int h = wid - g * N_HE;
    const int toff_tab[3] = {0, 167, 1048};
    int toff = toff_tab[g];
    const float* k2 = k2_all + (size_t)toff * E_DIM;
    const float* v2 = v2_all + (size_t)toff * E_DIM;
    const int* rows = rows_all + g * (N_HE + 1);
    const int* ebuf = ebuf_all + (size_t)g * E_EDGES;

    float qa = q_he[(size_t)h * E_DIM + lane];
    float qb = q_he[(size_t)h * E_DIM + 64 + lane];
    int start = rows[h], end = rows[h + 1];

    float m = -INFINITY, denom = 0.f, acca = 0.f, accb = 0.f;
    int i = start;
    for (; i + 2 <= end; i += 2) {
        int d0 = ebuf[i], d1 = ebuf[i + 1];
        const float* k0p = k2 + (size_t)d0 * E_DIM;
        const float* k1p = k2 + (size_t)d1 * E_DIM;
        float p0 = k0p[lane] * qa + k0p[64 + lane] * qb;
        float p1 = k1p[lane] * qa + k1p[64 + lane] * qb;
        wsum2(p0, p1);
        const float* v0p = v2 + (size_t)d0 * E_DIM;
        const float* v1p = v2 + (size_t)d1 * E_DIM;
        float v0a = v0p[lane], v0b = v0p[64 + lane];
        float v1a = v1p[lane], v1b = v1p[64 + lane];
        float s0 = p0 * SCALE; s0 = s0 > 0.f ? s0 : 0.01f * s0;
        float s1 = p1 * SCALE; s1 = s1 > 0.f ? s1 : 0.01f * s1;
        float newm = fmaxf(m, fmaxf(s0, s1));
        float scale = __expf(m - newm);
        float w0 = __expf(s0 - newm), w1 = __expf(s1 - newm);
        denom = denom * scale + w0 + w1;
        acca = fmaf(acca, scale, fmaf(w0, v0a, w1 * v1a));
        accb = fmaf(accb, scale, fmaf(w0, v0b, w1 * v1b));
        m = newm;
    }
    if (i < end) {
        int d0 = ebuf[i];
        const float* k0p = k2 + (size_t)d0 * E_DIM;
        float p0 = k0p[lane] * qa + k0p[64 + lane] * qb;
        float dummy = 0.f;
        wsum2(p0, dummy);
        const float* v0p = v2 + (size_t)d0 * E_DIM;
        float v0a = v0p[lane], v0b = v0p[64 + lane];
        float s0 = p0 * SCALE; s0 = s0 > 0.f ? s0 : 0.01f * s0;
        float newm = fmaxf(m, s0);
        float scale = __expf(m - newm);
        float w0 = __expf(s0 - newm);
        denom = denom * scale + w0;
        acca = fmaf(acca, scale, w0 * v0a);
        accb = fmaf(accb, scale, w0 * v0b);
        m = newm;
    }
    float rden = 1.f / fmaxf(denom, 1e-20f);
    float* out = he_new + (size_t)h * 384 + g * E_DIM;
    out[lane] = acca * rden;
    out[64 + lane] = accb * rden;
}

// ---------------- launch ----------------
extern "C" void kernel_launch(void* const* d_in, const int* in_sizes, int n_in,
                              void* d_out, int out_size, void* d_ws, size_t ws_size,
                              hipStream_t stream)
{
    const float* he_feat = (const float*)d_in[0];
    const float* w1w = (const float*)d_in[4];
    const float* w1b = (const float*)d_in[5];
    const float* w2w = (const float*)d_in[6];
    const float* w2b = (const float*)d_in[7];
    // d_in[8..11] = w3,w4 : dead code, unused
    const float* mlp1w = (const float*)d_in[30];
    const float* mlp1b = (const float*)d_in[31];
    const float* mlp2w = (const float*)d_in[32];
    const float* mlp2b = (const float*)d_in[33];
    const int* src_g[3] = {(const int*)d_in[34], (const int*)d_in[36], (const int*)d_in[38]};
    const int* dst_g[3] = {(const int*)d_in[35], (const int*)d_in[37], (const int*)d_in[39]};
    float* out = (float*)d_out;

    GroupPtrs Pq; // feat @ w5 + b5
    GroupPtrs Pkv; // qt @ w6/w7 + b6/b7
    for (int g = 0; g < 3; ++g) {
        Pq.feat[g] = (const float*)d_in[1 + g];
        Pq.wa[g] = (const float*)d_in[12 + 2 * g];
        Pq.ba[g] = (const float*)d_in[13 + 2 * g];
        Pq.wb[g] = nullptr;
        Pq.bb[g] = nullptr;
        Pkv.feat[g] = nullptr;
        Pkv.wa[g] = (const float*)d_in[18 + 4 * g]; // w6
        Pkv.ba[g] = (const float*)d_in[19 + 4 * g]; // b6
        Pkv.wb[g] = (const float*)d_in[20 + 4 * g]; // w7
        Pkv.bb[g] = (const float*)d_in[21 + 4 * g]; // b7
    }

    // workspace layout with lifetime aliasing (peak 128 MB):
    //   region X = [0, 51.2MB): phase-1 tenants (q_he, ebuf, ...), reused for h1 after attention.
    char* base = (char*)d_ws;
    size_t off = 0;
    auto alloc = [&](size_t bytes) {
        void* r = (void*)(base + off);
        off = (off + bytes + 255) & ~(size_t)255;
        return r;
    };
    float* q_he = (float*)alloc((size_t)N_HE * E_DIM * 4);      // 25.6 MB
    int* ebuf = (int*)alloc((size_t)3 * E_EDGES * 4);           // 14.4 MB
    float* W12 = (float*)alloc(IN_F * E_DIM * 4);
    float* b12 = (float*)alloc(E_DIM * 4);
    float* q_t = (float*)alloc(N_NODES * Q_DIM * 4);
    float* k2 = (float*)alloc(N_NODES * E_DIM * 4);
    float* v2 = (float*)alloc(N_NODES * E_DIM * 4);
    int* cnt = (int*)alloc(3 * N_HE * 4);
    int* rows = (int*)alloc(3 * (N_HE + 1) * 4);
    int* cursor = (int*)alloc(3 * N_HE * 4);
    size_t phase1_end = off;
    float* h1 = (float*)d_ws;                                    // aliases region X after attention
    size_t h1_bytes = (size_t)N_HE * 256 * 4;                    // 51.2 MB
    size_t he_new_off = ((phase1_end > h1_bytes ? phase1_end : h1_bytes) + 255) & ~(size_t)255;
    float* he_new = (float*)(base + he_new_off);                 // 76.8 MB

    hipMemsetAsync(cnt, 0, (size_t)3 * N_HE * 4, stream);

    // composed hyperedge projection weights (row-per-block split-K)
    compose_w12_kernel<<<IN_F + 1, 256, 0, stream>>>(w1w, w1b, w2w, w2b, W12, b12);

    // node projections (row-per-block split-K, fused across groups)
    node_q_fused_kernel<<<N_NODES, 256, 0, stream>>>(Pq, q_t);
    node_kv_fused_kernel<<<N_NODES, 256, 0, stream>>>(Pkv, q_t, k2, v2);

    // q_he = he_feat @ W12 + b12   [50000,128]
    {
        dim3 grid((N_HE + 63) / 64, E_DIM / 64);
        gemm_bias_kernel<false><<<grid, 256, 0, stream>>>(he_feat, W12, b12, q_he, N_HE, E_DIM, IN_F);
    }

    // CSR build per group
    {
        int grid_e = (E_EDGES + 255) / 256;
        for (int g = 0; g < 3; ++g)
            hist_kernel<<<grid_e, 256, 0, stream>>>(src_g[g], cnt + g * N_HE, E_EDGES);
        scan_kernel<<<3, 1024, 0, stream>>>(cnt, rows, cursor);
        for (int g = 0; g < 3; ++g)
            scatter_kernel<<<grid_e, 256, 0, stream>>>(src_g[g], dst_g[g], cursor + g * N_HE,
                                                       ebuf + (size_t)g * E_EDGES, E_EDGES);
    }

    // attention: one wave per (group, hyperedge)
    attn_kernel<<<(3 * N_HE) / 4, 256, 0, stream>>>(q_he, k2, v2, rows, ebuf, he_new);

    // MLP (h1 aliases the now-dead q_he/ebuf region)
    {
        dim3 grid1((N_HE + 63) / 64, 256 / 64);
        gemm_bias_kernel<true><<<grid1, 256, 0, stream>>>(he_new, mlp1w, mlp1b, h1, N_HE, 256, 384);
        dim3 grid2((N_HE + 63) / 64, 128 / 64);
        gemm_bias_kernel<true><<<grid2, 256, 0, stream>>>(h1, mlp2w, mlp2b, out, N_HE, 128, 256);
    }
}

// Round 4
// 939.357 us; speedup vs baseline: 1.6540x; 1.2893x over previous
//
#include <hip/hip_runtime.h>
#include <hip/hip_bf16.h>

constexpr int N_HE = 50000;
constexpr int E_EDGES = 1200000;
constexpr int IN_F = 200;
constexpr int HE_DIM = 512;
constexpr int E_DIM = 128;
constexpr int Q_DIM = 64;
constexpr float SCALE = 0.125f; // 1/sqrt(64)
constexpr int N_NODES = 167 + 881 + 441; // 1489

struct GroupPtrs {
    const float* feat[3];
    const float* wa[3];
    const float* ba[3];
    const float* wb[3];
    const float* bb[3];
};

// ---------------- compose W12 = w1_w @ w2_w (row 200 = bias row) ----------------
__global__ __launch_bounds__(256) void compose_w12_kernel(
    const float* __restrict__ w1w, const float* __restrict__ w1b,
    const float* __restrict__ w2w, const float* __restrict__ w2b,
    float* __restrict__ W12, float* __restrict__ b12)
{
    int row = blockIdx.x; // 0..200
    int col = threadIdx.x & 127, ks = threadIdx.x >> 7;
    const float* a = (row < IN_F) ? (w1w + (size_t)row * HE_DIM) : w1b;
    float s = 0.f;
#pragma unroll 4
    for (int k = ks; k < HE_DIM; k += 2)
        s = fmaf(a[k], w2w[k * E_DIM + col], s);
    __shared__ float red[2][128];
    red[ks][col] = s;
    __syncthreads();
    if (ks == 0) {
        float v = red[0][col] + red[1][col];
        if (row < IN_F) W12[row * E_DIM + col] = v;
        else b12[col] = v + w2b[col];
    }
}

// ---------------- fused node q projection: one block per node row ----------------
__global__ __launch_bounds__(256) void node_q_fused_kernel(GroupPtrs P, float* __restrict__ qt)
{
    int b = blockIdx.x; // 0..1488
    int g = (b < 167) ? 0 : (b < 1048 ? 1 : 2);
    int row = b - (g == 0 ? 0 : (g == 1 ? 167 : 1048));
    int Dt = (g == 0) ? 167 : (g == 1 ? 881 : 441);
    const float* feat = P.feat[g] + (size_t)row * Dt;
    const float* w5 = P.wa[g];
    int col = threadIdx.x & 63, ks = threadIdx.x >> 6; // 4 k-slices
    float s = 0.f;
#pragma unroll 4
    for (int k = ks; k < Dt; k += 4)
        s = fmaf(feat[k], w5[k * Q_DIM + col], s);
    __shared__ float red[4][64];
    red[ks][col] = s;
    __syncthreads();
    if (ks == 0) {
        qt[(size_t)b * Q_DIM + col] =
            red[0][col] + red[1][col] + red[2][col] + red[3][col] + P.ba[g][col];
    }
}

// ---------------- fused node k2/v2 projection -> packed kv2[n][256] ----------------
__global__ __launch_bounds__(256) void node_kv_fused_kernel(
    GroupPtrs P, const float* __restrict__ qt, float* __restrict__ kv2)
{
    int b = blockIdx.x; // 0..1488
    int g = (b < 167) ? 0 : (b < 1048 ? 1 : 2);
    int col = threadIdx.x & 127, ks = threadIdx.x >> 7; // 2 k-slices of 32
    const float* w6 = P.wa[g];
    const float* w7 = P.wb[g];
    const float* q = qt + (size_t)b * Q_DIM;
    float s1 = 0.f, s2 = 0.f;
#pragma unroll 8
    for (int k = ks * 32; k < ks * 32 + 32; ++k) {
        float qv = q[k];
        s1 = fmaf(qv, w6[k * E_DIM + col], s1);
        s2 = fmaf(qv, w7[k * E_DIM + col], s2);
    }
    __shared__ float r1[2][128], r2[2][128];
    r1[ks][col] = s1;
    r2[ks][col] = s2;
    __syncthreads();
    if (ks == 0) {
        kv2[(size_t)b * 256 + col] = r1[0][col] + r1[1][col] + P.ba[g][col];
        kv2[(size_t)b * 256 + 128 + col] = r2[0][col] + r2[1][col] + P.bb[g][col];
    }
}

// ---------------- tiled f32 GEMM 128x64, 8x4/thread: C = A@B + bias, opt relu ----------------
// K must be a multiple of 8 (true here: 200, 384, 256); N a multiple of 4.
template <bool RELU>
__global__ __launch_bounds__(256) void gemm_bias_kernel(
    const float* __restrict__ A, const float* __restrict__ B, const float* __restrict__ bias,
    float* __restrict__ C, int M, int N, int K)
{
    __shared__ float As[16][132];
    __shared__ float Bs[16][68];
    const int tid = threadIdx.x;
    const int bm = blockIdx.x * 128, bn = blockIdx.y * 64;
    const int ty = tid >> 4, tx = tid & 15;
    const int arow = tid >> 1, akk = (tid & 1) * 8;
    float acc[8][4] = {};
    for (int k0 = 0; k0 < K; k0 += 16) {
        // stage A: 128x16, two float4 per thread, transposed store
        {
            int row = bm + arow;
            float4 av0 = {0, 0, 0, 0}, av1 = {0, 0, 0, 0};
            if (row < M && (k0 + akk) < K) {
                const float* ap = A + (size_t)row * K + k0 + akk;
                av0 = *reinterpret_cast<const float4*>(ap);
                av1 = *reinterpret_cast<const float4*>(ap + 4);
            }
            As[akk + 0][arow] = av0.x; As[akk + 1][arow] = av0.y;
            As[akk + 2][arow] = av0.z; As[akk + 3][arow] = av0.w;
            As[akk + 4][arow] = av1.x; As[akk + 5][arow] = av1.y;
            As[akk + 6][arow] = av1.z; As[akk + 7][arow] = av1.w;
        }
        // stage B: 16x64, one float4 per thread
        {
            int kB = k0 + (tid >> 4);
            int col = bn + (tid & 15) * 4;
            float4 bv = {0, 0, 0, 0};
            if (kB < K && col < N)
                bv = *reinterpret_cast<const float4*>(B + (size_t)kB * N + col);
            *reinterpret_cast<float4*>(&Bs[tid >> 4][(tid & 15) * 4]) = bv;
        }
        __syncthreads();
#pragma unroll
        for (int kk = 0; kk < 16; ++kk) {
            float4 a0 = *reinterpret_cast<const float4*>(&As[kk][ty * 8]);
            float4 a1 = *reinterpret_cast<const float4*>(&As[kk][ty * 8 + 4]);
            float4 b = *reinterpret_cast<const float4*>(&Bs[kk][tx * 4]);
            float am[8] = {a0.x, a0.y, a0.z, a0.w, a1.x, a1.y, a1.z, a1.w};
            float bn4[4] = {b.x, b.y, b.z, b.w};
#pragma unroll
            for (int i2 = 0; i2 < 8; ++i2)
#pragma unroll
                for (int j2 = 0; j2 < 4; ++j2)
                    acc[i2][j2] = fmaf(am[i2], bn4[j2], acc[i2][j2]);
        }
        __syncthreads();
    }
    int col = bn + tx * 4;
    float4 bb4 = {0, 0, 0, 0};
    if (col + 3 < N) bb4 = *reinterpret_cast<const float4*>(bias + col);
#pragma unroll
    for (int i2 = 0; i2 < 8; ++i2) {
        int row = bm + ty * 8 + i2;
        if (row >= M || col + 3 >= N) continue;
        float4 v;
        v.x = acc[i2][0] + bb4.x; v.y = acc[i2][1] + bb4.y;
        v.z = acc[i2][2] + bb4.z; v.w = acc[i2][3] + bb4.w;
        if (RELU) {
            v.x = fmaxf(v.x, 0.f); v.y = fmaxf(v.y, 0.f);
            v.z = fmaxf(v.z, 0.f); v.w = fmaxf(v.w, 0.f);
        }
        *reinterpret_cast<float4*>(C + (size_t)row * N + col) = v;
    }
}

// ---------------- CSR build ----------------
__global__ __launch_bounds__(256) void hist_kernel(const int* __restrict__ src, int* __restrict__ cnt, int n)
{
    int i = blockIdx.x * 256 + threadIdx.x;
    if (i < n) atomicAdd(&cnt[src[i]], 1);
}

__global__ __launch_bounds__(1024) void scan_kernel(const int* __restrict__ cnt,
                                                    int* __restrict__ rows,
                                                    int* __restrict__ cursor)
{
    int g = blockIdx.x;
    const int* c = cnt + g * N_HE;
    int* r = rows + g * (N_HE + 1);
    int* cur = cursor + g * N_HE;
    __shared__ int wsum[16];
    __shared__ int s_running;
    int tid = threadIdx.x, lane = tid & 63, w = tid >> 6;
    if (tid == 0) s_running = 0;
    __syncthreads();
    for (int base = 0; base < N_HE; base += 1024) {
        int i = base + tid;
        int v = (i < N_HE) ? c[i] : 0;
        int x = v;
#pragma unroll
        for (int off = 1; off < 64; off <<= 1) {
            int t = __shfl_up(x, off, 64);
            if (lane >= off) x += t;
        }
        if (lane == 63) wsum[w] = x;
        __syncthreads();
        if (w == 0 && lane < 16) {
            int s = wsum[lane];
#pragma unroll
            for (int off = 1; off < 16; off <<= 1) {
                int t = __shfl_up(s, off, 64);
                if (lane >= off) s += t;
            }
            wsum[lane] = s;
        }
        __syncthreads();
        int woff = (w == 0) ? 0 : wsum[w - 1];
        int total = wsum[15];
        int excl = s_running + woff + x - v;
        if (i < N_HE) { r[i] = excl; cur[i] = excl; }
        __syncthreads();
        if (tid == 0) s_running += total;
        __syncthreads();
    }
    if (tid == 0) r[N_HE] = s_running;
}

__global__ __launch_bounds__(256) void scatter_kernel(const int* __restrict__ src, const int* __restrict__ dst,
                                                      int* __restrict__ cursor, int* __restrict__ ebuf, int n)
{
    int i = blockIdx.x * 256 + threadIdx.x;
    if (i < n) {
        int pos = atomicAdd(&cursor[src[i]], 1);
        ebuf[pos] = dst[i];
    }
}

// ---------------- attention: wave per hyperedge, 16-lane subgroups, online softmax ----------------
__global__ __launch_bounds__(256) void attn_kernel(
    const float* __restrict__ q_he,   // [N_HE,128]
    const float* __restrict__ kv2,    // [1489][256] packed k|v
    const int* __restrict__ rows_all, // 3*(N_HE+1)
    const int* __restrict__ ebuf_all, // 3*E
    float* __restrict__ he_new)       // [N_HE,384]
{
    int wid = blockIdx.x * 4 + (threadIdx.x >> 6);
    int lane = threadIdx.x & 63;
    int g = wid / N_HE;
    int h = wid - g * N_HE;
    const int toff_tab[3] = {0, 167, 1048};
    const float* kv = kv2 + (size_t)toff_tab[g] * 256;
    const int* rows = rows_all + g * (N_HE + 1);
    const int* ebuf = ebuf_all + (size_t)g * E_EDGES;

    int sub = lane >> 4, sl = lane & 15;
    const float* qp = q_he + (size_t)h * 128 + sl * 8;
    float4 q0 = *reinterpret_cast<const float4*>(qp);
    float4 q1 = *reinterpret_cast<const float4*>(qp + 4);

    int start = rows[h], end = rows[h + 1];
    float m = -INFINITY, denom = 0.f;
    float acc[8] = {};

    for (int i0 = start + sub * 2; i0 < end; i0 += 8) {
        bool ok1 = (i0 + 1) < end;
        int d0 = ebuf[i0];
        int d1 = ebuf[ok1 ? i0 + 1 : i0];
        const float* k0 = kv + (size_t)d0 * 256 + sl * 8;
        const float* k1 = kv + (size_t)d1 * 256 + sl * 8;
        float4 a0 = *reinterpret_cast<const float4*>(k0);
        float4 b0 = *reinterpret_cast<const float4*>(k0 + 4);
        float4 a1 = *reinterpret_cast<const float4*>(k1);
        float4 b1 = *reinterpret_cast<const float4*>(k1 + 4);
        float p0 = q0.x * a0.x;
        p0 = fmaf(q0.y, a0.y, p0); p0 = fmaf(q0.z, a0.z, p0); p0 = fmaf(q0.w, a0.w, p0);
        p0 = fmaf(q1.x, b0.x, p0); p0 = fmaf(q1.y, b0.y, p0);
        p0 = fmaf(q1.z, b0.z, p0); p0 = fmaf(q1.w, b0.w, p0);
        float p1 = q0.x * a1.x;
        p1 = fmaf(q0.y, a1.y, p1); p1 = fmaf(q0.z, a1.z, p1); p1 = fmaf(q0.w, a1.w, p1);
        p1 = fmaf(q1.x, b1.x, p1); p1 = fmaf(q1.y, b1.y, p1);
        p1 = fmaf(q1.z, b1.z, p1); p1 = fmaf(q1.w, b1.w, p1);
#pragma unroll
        for (int mask = 1; mask < 16; mask <<= 1) {
            p0 += __shfl_xor(p0, mask, 64);
            p1 += __shfl_xor(p1, mask, 64);
        }
        float s0 = p0 * SCALE; s0 = s0 > 0.f ? s0 : 0.01f * s0;
        float s1 = p1 * SCALE; s1 = s1 > 0.f ? s1 : 0.01f * s1;
        if (!ok1) s1 = -INFINITY;
        float newm = fmaxf(fmaxf(s0, s1), m);
        float scale = __expf(m - newm);
        float w0 = __expf(s0 - newm);
        float w1 = __expf(s1 - newm);
        denom = fmaf(denom, scale, w0 + w1);
        const float* v0 = k0 + 128;
        const float* v1 = k1 + 128;
        float4 va0 = *reinterpret_cast<const float4*>(v0);
        float4 vb0 = *reinterpret_cast<const float4*>(v0 + 4);
        float4 va1 = *reinterpret_cast<const float4*>(v1);
        float4 vb1 = *reinterpret_cast<const float4*>(v1 + 4);
        float v0a[8] = {va0.x, va0.y, va0.z, va0.w, vb0.x, vb0.y, vb0.z, vb0.w};
        float v1a[8] = {va1.x, va1.y, va1.z, va1.w, vb1.x, vb1.y, vb1.z, vb1.w};
#pragma unroll
        for (int j = 0; j < 8; ++j)
            acc[j] = fmaf(w0, v0a[j], fmaf(w1, v1a[j], acc[j] * scale));
        m = newm;
    }

    // merge the 4 subgroup states
    float om = fmaxf(m, __shfl_xor(m, 16, 64));
    om = fmaxf(om, __shfl_xor(om, 32, 64));
    float f = (denom > 0.f) ? __expf(m - om) : 0.f;
    float d = denom * f;
    d += __shfl_xor(d, 16, 64);
    d += __shfl_xor(d, 32, 64);
#pragma unroll
    for (int j = 0; j < 8; ++j) {
        float a = acc[j] * f;
        a += __shfl_xor(a, 16, 64);
        a += __shfl_xor(a, 32, 64);
        acc[j] = a;
    }
    if (sub == 0) {
        float rden = 1.f / fmaxf(d, 1e-20f);
        float* out = he_new + (size_t)h * 384 + g * 128 + sl * 8;
        float4 o0 = {acc[0] * rden, acc[1] * rden, acc[2] * rden, acc[3] * rden};
        float4 o1 = {acc[4] * rden, acc[5] * rden, acc[6] * rden, acc[7] * rden};
        *reinterpret_cast<float4*>(out) = o0;
        *reinterpret_cast<float4*>(out + 4) = o1;
    }
}

// ---------------- launch ----------------
extern "C" void kernel_launch(void* const* d_in, const int* in_sizes, int n_in,
                              void* d_out, int out_size, void* d_ws, size_t ws_size,
                              hipStream_t stream)
{
    const float* he_feat = (const float*)d_in[0];
    const float* w1w = (const float*)d_in[4];
    const float* w1b = (const float*)d_in[5];
    const float* w2w = (const float*)d_in[6];
    const float* w2b = (const float*)d_in[7];
    const float* mlp1w = (const float*)d_in[30];
    const float* mlp1b = (const float*)d_in[31];
    const float* mlp2w = (const float*)d_in[32];
    const float* mlp2b = (const float*)d_in[33];
    const int* src_g[3] = {(const int*)d_in[34], (const int*)d_in[36], (const int*)d_in[38]};
    const int* dst_g[3] = {(const int*)d_in[35], (const int*)d_in[37], (const int*)d_in[39]};
    float* out = (float*)d_out;

    GroupPtrs Pq, Pkv;
    for (int g = 0; g < 3; ++g) {
        Pq.feat[g] = (const float*)d_in[1 + g];
        Pq.wa[g] = (const float*)d_in[12 + 2 * g];
        Pq.ba[g] = (const float*)d_in[13 + 2 * g];
        Pq.wb[g] = nullptr; Pq.bb[g] = nullptr;
        Pkv.feat[g] = nullptr;
        Pkv.wa[g] = (const float*)d_in[18 + 4 * g]; // w6
        Pkv.ba[g] = (const float*)d_in[19 + 4 * g]; // b6
        Pkv.wb[g] = (const float*)d_in[20 + 4 * g]; // w7
        Pkv.bb[g] = (const float*)d_in[21 + 4 * g]; // b7
    }

    char* base = (char*)d_ws;
    size_t off = 0;
    auto alloc = [&](size_t bytes) {
        void* r = (void*)(base + off);
        off = (off + bytes + 255) & ~(size_t)255;
        return r;
    };
    float* q_he = (float*)alloc((size_t)N_HE * E_DIM * 4);      // 25.6 MB
    int* ebuf = (int*)alloc((size_t)3 * E_EDGES * 4);           // 14.4 MB
    float* W12 = (float*)alloc(IN_F * E_DIM * 4);
    float* b12 = (float*)alloc(E_DIM * 4);
    float* q_t = (float*)alloc(N_NODES * Q_DIM * 4);
    float* kv2 = (float*)alloc((size_t)N_NODES * 256 * 4);
    int* cnt = (int*)alloc(3 * N_HE * 4);
    int* rows = (int*)alloc(3 * (N_HE + 1) * 4);
    int* cursor = (int*)alloc(3 * N_HE * 4);
    size_t phase1_end = off;
    float* h1 = (float*)d_ws;                                    // aliases phase-1 region after attention
    size_t h1_bytes = (size_t)N_HE * 256 * 4;                    // 51.2 MB
    size_t he_new_off = ((phase1_end > h1_bytes ? phase1_end : h1_bytes) + 255) & ~(size_t)255;
    float* he_new = (float*)(base + he_new_off);                 // 76.8 MB

    hipMemsetAsync(cnt, 0, (size_t)3 * N_HE * 4, stream);

    compose_w12_kernel<<<IN_F + 1, 256, 0, stream>>>(w1w, w1b, w2w, w2b, W12, b12);
    node_q_fused_kernel<<<N_NODES, 256, 0, stream>>>(Pq, q_t);
    node_kv_fused_kernel<<<N_NODES, 256, 0, stream>>>(Pkv, q_t, kv2);

    // q_he = he_feat @ W12 + b12   [50000,128]
    {
        dim3 grid((N_HE + 127) / 128, E_DIM / 64);
        gemm_bias_kernel<false><<<grid, 256, 0, stream>>>(he_feat, W12, b12, q_he, N_HE, E_DIM, IN_F);
    }

    // CSR build per group
    {
        int grid_e = (E_EDGES + 255) / 256;
        for (int g = 0; g < 3; ++g)
            hist_kernel<<<grid_e, 256, 0, stream>>>(src_g[g], cnt + g * N_HE, E_EDGES);
        scan_kernel<<<3, 1024, 0, stream>>>(cnt, rows, cursor);
        for (int g = 0; g < 3; ++g)
            scatter_kernel<<<grid_e, 256, 0, stream>>>(src_g[g], dst_g[g], cursor + g * N_HE,
                                                       ebuf + (size_t)g * E_EDGES, E_EDGES);
    }

    attn_kernel<<<(3 * N_HE) / 4, 256, 0, stream>>>(q_he, kv2, rows, ebuf, he_new);

    // MLP (h1 aliases the now-dead q_he/ebuf region)
    {
        dim3 grid1((N_HE + 127) / 128, 256 / 64);
        gemm_bias_kernel<true><<<grid1, 256, 0, stream>>>(he_new, mlp1w, mlp1b, h1, N_HE, 256, 384);
        dim3 grid2((N_HE + 127) / 128, 128 / 64);
        gemm_bias_kernel<true><<<grid2, 256, 0, stream>>>(h1, mlp2w, mlp2b, out, N_HE, 128, 256);
    }
}

// Round 6
// 835.953 us; speedup vs baseline: 1.8586x; 1.1237x over previous
//
#include <hip/hip_runtime.h>
#include <hip/hip_bf16.h>

constexpr int N_HE = 50000;
constexpr int E_EDGES = 1200000;
constexpr int IN_F = 200;
constexpr int HE_DIM = 512;
constexpr int E_DIM = 128;
constexpr int Q_DIM = 64;
constexpr float SCALE = 0.125f; // 1/sqrt(64)
constexpr int N_NODES = 167 + 881 + 441; // 1489
constexpr int R_STRIDE = 216;  // 3 groups x 72 (64 r-cols + 1 c-col + 7 pad)
constexpr int T_STRIDE = 192;  // 3 groups x 64

struct GroupPtrs {
    const float* feat[3];
    const float* wa[3];
    const float* ba[3];
    const float* wb[3];
    const float* bb[3];
};

// ---------------- compose W12 = w1_w @ w2_w (row 200 = bias row) ----------------
__global__ __launch_bounds__(256) void compose_w12_kernel(
    const float* __restrict__ w1w, const float* __restrict__ w1b,
    const float* __restrict__ w2w, const float* __restrict__ w2b,
    float* __restrict__ W12, float* __restrict__ b12)
{
    int row = blockIdx.x; // 0..200
    int col = threadIdx.x & 127, ks = threadIdx.x >> 7;
    const float* a = (row < IN_F) ? (w1w + (size_t)row * HE_DIM) : w1b;
    float s = 0.f;
#pragma unroll 4
    for (int k = ks; k < HE_DIM; k += 2)
        s = fmaf(a[k], w2w[k * E_DIM + col], s);
    __shared__ float red[2][128];
    red[ks][col] = s;
    __syncthreads();
    if (ks == 0) {
        float v = red[0][col] + red[1][col];
        if (row < IN_F) W12[row * E_DIM + col] = v;
        else b12[col] = v + w2b[col];
    }
}

// ---------------- B_kv[128][216]: per group cols g*72+j : j<64 -> w6_g^T, j==64 -> b6_g ----------------
__global__ __launch_bounds__(256) void prep_bkv_kernel(
    const float* __restrict__ w6m, const float* __restrict__ b6m,
    const float* __restrict__ w6p, const float* __restrict__ b6p,
    const float* __restrict__ w6e, const float* __restrict__ b6e,
    float* __restrict__ B)
{
    int k = blockIdx.x;   // 0..127
    int c = threadIdx.x;  // 0..255
    if (c >= R_STRIDE) return;
    int g = c / 72, j = c - g * 72;
    const float* w6 = (g == 0) ? w6m : (g == 1) ? w6p : w6e;
    const float* b6 = (g == 0) ? b6m : (g == 1) ? b6p : b6e;
    float v = 0.f;
    if (j < 64) v = w6[j * E_DIM + k];
    else if (j == 64) v = b6[k];
    B[k * R_STRIDE + c] = v;
}

// ---------------- W_comp[192][256] = blockdiag(w7_g) @ mlp1_w ; b_comp = mlp1_b + sum b7_g @ mlp1_w_g ----------------
__global__ __launch_bounds__(256) void prep_wcomp_kernel(
    const float* __restrict__ w7m, const float* __restrict__ b7m,
    const float* __restrict__ w7p, const float* __restrict__ b7p,
    const float* __restrict__ w7e, const float* __restrict__ b7e,
    const float* __restrict__ mlp1w, const float* __restrict__ mlp1b,
    float* __restrict__ Wc, float* __restrict__ bc)
{
    int row = blockIdx.x; // 0..192 (192 = bias row)
    int n = threadIdx.x;  // 0..255
    if (row < 192) {
        int g = row >> 6, i = row & 63;
        const float* w7 = (g == 0) ? w7m : (g == 1) ? w7p : w7e;
        float s = 0.f;
#pragma unroll 4
        for (int k = 0; k < 128; ++k)
            s = fmaf(w7[i * 128 + k], mlp1w[(size_t)(g * 128 + k) * 256 + n], s);
        Wc[(size_t)row * 256 + n] = s;
    } else {
        const float* b7s[3] = {b7m, b7p, b7e};
        float s = mlp1b[n];
        for (int g = 0; g < 3; ++g)
#pragma unroll 4
            for (int k = 0; k < 128; ++k)
                s = fmaf(b7s[g][k], mlp1w[(size_t)(g * 128 + k) * 256 + n], s);
        bc[n] = s;
    }
}

// ---------------- fused node q projection: one block per node row ----------------
__global__ __launch_bounds__(256) void node_q_fused_kernel(GroupPtrs P, float* __restrict__ qt)
{
    int b = blockIdx.x; // 0..1488
    int g = (b < 167) ? 0 : (b < 1048 ? 1 : 2);
    int row = b - (g == 0 ? 0 : (g == 1 ? 167 : 1048));
    int Dt = (g == 0) ? 167 : (g == 1 ? 881 : 441);
    const float* feat = P.feat[g] + (size_t)row * Dt;
    const float* w5 = P.wa[g];
    int col = threadIdx.x & 63, ks = threadIdx.x >> 6; // 4 k-slices
    float s = 0.f;
#pragma unroll 4
    for (int k = ks; k < Dt; k += 4)
        s = fmaf(feat[k], w5[k * Q_DIM + col], s);
    __shared__ float red[4][64];
    red[ks][col] = s;
    __syncthreads();
    if (ks == 0) {
        qt[(size_t)b * Q_DIM + col] =
            red[0][col] + red[1][col] + red[2][col] + red[3][col] + P.ba[g][col];
    }
}

// ---------------- tiled f32 GEMM 128x64, 8x4/thread: C = A@B (+ bias), opt relu ----------------
template <bool RELU>
__global__ __launch_bounds__(256) void gemm_bias_kernel(
    const float* __restrict__ A, const float* __restrict__ B, const float* __restrict__ bias,
    float* __restrict__ C, int M, int N, int K)
{
    __shared__ float As[16][132];
    __shared__ float Bs[16][68];
    const int tid = threadIdx.x;
    const int bm = blockIdx.x * 128, bn = blockIdx.y * 64;
    const int ty = tid >> 4, tx = tid & 15;
    const int arow = tid >> 1, akk = (tid & 1) * 8;
    float acc[8][4] = {};
    for (int k0 = 0; k0 < K; k0 += 16) {
        {
            int row = bm + arow;
            float4 av0 = {0, 0, 0, 0}, av1 = {0, 0, 0, 0};
            if (row < M && (k0 + akk) < K) {
                const float* ap = A + (size_t)row * K + k0 + akk;
                av0 = *reinterpret_cast<const float4*>(ap);
                av1 = *reinterpret_cast<const float4*>(ap + 4);
            }
            As[akk + 0][arow] = av0.x; As[akk + 1][arow] = av0.y;
            As[akk + 2][arow] = av0.z; As[akk + 3][arow] = av0.w;
            As[akk + 4][arow] = av1.x; As[akk + 5][arow] = av1.y;
            As[akk + 6][arow] = av1.z; As[akk + 7][arow] = av1.w;
        }
        {
            int kB = k0 + (tid >> 4);
            int col = bn + (tid & 15) * 4;
            float4 bv = {0, 0, 0, 0};
            if (kB < K && col < N)
                bv = *reinterpret_cast<const float4*>(B + (size_t)kB * N + col);
            *reinterpret_cast<float4*>(&Bs[tid >> 4][(tid & 15) * 4]) = bv;
        }
        __syncthreads();
#pragma unroll
        for (int kk = 0; kk < 16; ++kk) {
            float4 a0 = *reinterpret_cast<const float4*>(&As[kk][ty * 8]);
            float4 a1 = *reinterpret_cast<const float4*>(&As[kk][ty * 8 + 4]);
            float4 b = *reinterpret_cast<const float4*>(&Bs[kk][tx * 4]);
            float am[8] = {a0.x, a0.y, a0.z, a0.w, a1.x, a1.y, a1.z, a1.w};
            float bn4[4] = {b.x, b.y, b.z, b.w};
#pragma unroll
            for (int i2 = 0; i2 < 8; ++i2)
#pragma unroll
                for (int j2 = 0; j2 < 4; ++j2)
                    acc[i2][j2] = fmaf(am[i2], bn4[j2], acc[i2][j2]);
        }
        __syncthreads();
    }
    int col = bn + tx * 4;
    float4 bb4 = {0, 0, 0, 0};
    if (bias && col + 3 < N) bb4 = *reinterpret_cast<const float4*>(bias + col);
#pragma unroll
    for (int i2 = 0; i2 < 8; ++i2) {
        int row = bm + ty * 8 + i2;
        if (row >= M || col + 3 >= N) continue;
        float4 v;
        v.x = acc[i2][0] + bb4.x; v.y = acc[i2][1] + bb4.y;
        v.z = acc[i2][2] + bb4.z; v.w = acc[i2][3] + bb4.w;
        if (RELU) {
            v.x = fmaxf(v.x, 0.f); v.y = fmaxf(v.y, 0.f);
            v.z = fmaxf(v.z, 0.f); v.w = fmaxf(v.w, 0.f);
        }
        *reinterpret_cast<float4*>(C + (size_t)row * N + col) = v;
    }
}

// ---------------- CSR build ----------------
__global__ __launch_bounds__(256) void hist_kernel(const int* __restrict__ src, int* __restrict__ cnt, int n)
{
    int i = blockIdx.x * 256 + threadIdx.x;
    if (i < n) atomicAdd(&cnt[src[i]], 1);
}

__global__ __launch_bounds__(1024) void scan_kernel(const int* __restrict__ cnt,
                                                    int* __restrict__ rows,
                                                    int* __restrict__ cursor)
{
    int g = blockIdx.x;
    const int* c = cnt + g * N_HE;
    int* r = rows + g * (N_HE + 1);
    int* cur = cursor + g * N_HE;
    __shared__ int wsum[16];
    __shared__ int s_running;
    int tid = threadIdx.x, lane = tid & 63, w = tid >> 6;
    if (tid == 0) s_running = 0;
    __syncthreads();
    for (int base = 0; base < N_HE; base += 1024) {
        int i = base + tid;
        int v = (i < N_HE) ? c[i] : 0;
        int x = v;
#pragma unroll
        for (int off = 1; off < 64; off <<= 1) {
            int t = __shfl_up(x, off, 64);
            if (lane >= off) x += t;
        }
        if (lane == 63) wsum[w] = x;
        __syncthreads();
        if (w == 0 && lane < 16) {
            int s = wsum[lane];
#pragma unroll
            for (int off = 1; off < 16; off <<= 1) {
                int t = __shfl_up(s, off, 64);
                if (lane >= off) s += t;
            }
            wsum[lane] = s;
        }
        __syncthreads();
        int woff = (w == 0) ? 0 : wsum[w - 1];
        int total = wsum[15];
        int excl = s_running + woff + x - v;
        if (i < N_HE) { r[i] = excl; cur[i] = excl; }
        __syncthreads();
        if (tid == 0) s_running += total;
        __syncthreads();
    }
    if (tid == 0) r[N_HE] = s_running;
}

__global__ __launch_bounds__(256) void scatter_kernel(const int* __restrict__ src, const int* __restrict__ dst,
                                                      int* __restrict__ cursor, int* __restrict__ ebuf, int n)
{
    int i = blockIdx.x * 256 + threadIdx.x;
    if (i < n) {
        int pos = atomicAdd(&cursor[src[i]], 1);
        ebuf[pos] = dst[i];
    }
}

// ---------------- attention on reduced 64-dim states ----------------
// score_e = leaky_relu((<q_t[d_e], r_h> + c_h) * SCALE); T[h] = softmax-weighted avg of q_t rows.
// Loop structure mirrors the round-4 PASSED kernel exactly: per-subgroup pair stride,
// direct ebuf reads, no staged/dynamic shuffles.
__global__ __launch_bounds__(256) void attn_kernel(
    const float* __restrict__ R,      // [N_HE][216]
    const float* __restrict__ q_t,    // [1489][64]
    const int* __restrict__ rows_all, // 3*(N_HE+1)
    const int* __restrict__ ebuf_all, // 3*E
    float* __restrict__ T)            // [N_HE][192]
{
    int wid = blockIdx.x * 4 + (threadIdx.x >> 6);
    int lane = threadIdx.x & 63;
    int g = wid / N_HE;
    int h = wid - g * N_HE;
    const int toff_tab[3] = {0, 167, 1048};
    const float* qt = q_t + (size_t)toff_tab[g] * Q_DIM;
    const int* rows = rows_all + g * (N_HE + 1);
    const int* ebuf = ebuf_all + (size_t)g * E_EDGES;
    int start = rows[h], end = rows[h + 1];

    int sub = lane >> 4, sl = lane & 15;
    const float* Rrow = R + (size_t)h * R_STRIDE + g * 72;
    float4 r4 = *reinterpret_cast<const float4*>(Rrow + sl * 4);
    float ch = Rrow[64];

    float m = -INFINITY, denom = 0.f;
    float acc0 = 0.f, acc1 = 0.f, acc2 = 0.f, acc3 = 0.f;

    for (int i0 = start + sub * 2; i0 < end; i0 += 8) {
        bool ok1 = (i0 + 1) < end;
        int d0 = ebuf[i0];
        int d1 = ebuf[ok1 ? i0 + 1 : i0];
        float4 t0 = *reinterpret_cast<const float4*>(qt + (size_t)d0 * Q_DIM + sl * 4);
        float4 t1 = *reinterpret_cast<const float4*>(qt + (size_t)d1 * Q_DIM + sl * 4);
        float p0 = t0.x * r4.x;
        p0 = fmaf(t0.y, r4.y, p0); p0 = fmaf(t0.z, r4.z, p0); p0 = fmaf(t0.w, r4.w, p0);
        float p1 = t1.x * r4.x;
        p1 = fmaf(t1.y, r4.y, p1); p1 = fmaf(t1.z, r4.z, p1); p1 = fmaf(t1.w, r4.w, p1);
#pragma unroll
        for (int mask = 1; mask < 16; mask <<= 1) {
            p0 += __shfl_xor(p0, mask, 64);
            p1 += __shfl_xor(p1, mask, 64);
        }
        float s0 = (p0 + ch) * SCALE; s0 = s0 > 0.f ? s0 : 0.01f * s0;
        float s1 = (p1 + ch) * SCALE; s1 = s1 > 0.f ? s1 : 0.01f * s1;
        if (!ok1) s1 = -INFINITY;
        float newm = fmaxf(fmaxf(s0, s1), m);
        float sc = __expf(m - newm);
        float w0 = __expf(s0 - newm);
        float w1 = __expf(s1 - newm);
        denom = fmaf(denom, sc, w0 + w1);
        acc0 = fmaf(w0, t0.x, fmaf(w1, t1.x, acc0 * sc));
        acc1 = fmaf(w0, t0.y, fmaf(w1, t1.y, acc1 * sc));
        acc2 = fmaf(w0, t0.z, fmaf(w1, t1.z, acc2 * sc));
        acc3 = fmaf(w0, t0.w, fmaf(w1, t1.w, acc3 * sc));
        m = newm;
    }

    // merge the 4 subgroup states (same 4 dims per sl across subs)
    float om = fmaxf(m, __shfl_xor(m, 16, 64));
    om = fmaxf(om, __shfl_xor(om, 32, 64));
    float f = (denom > 0.f) ? __expf(m - om) : 0.f;
    float d = denom * f;
    d += __shfl_xor(d, 16, 64);
    d += __shfl_xor(d, 32, 64);
    float a0 = acc0 * f, a1 = acc1 * f, a2 = acc2 * f, a3 = acc3 * f;
    a0 += __shfl_xor(a0, 16, 64); a0 += __shfl_xor(a0, 32, 64);
    a1 += __shfl_xor(a1, 16, 64); a1 += __shfl_xor(a1, 32, 64);
    a2 += __shfl_xor(a2, 16, 64); a2 += __shfl_xor(a2, 32, 64);
    a3 += __shfl_xor(a3, 16, 64); a3 += __shfl_xor(a3, 32, 64);
    if (sub == 0) {
        float rden = 1.f / fmaxf(d, 1e-20f);
        float4 o = {a0 * rden, a1 * rden, a2 * rden, a3 * rden};
        *reinterpret_cast<float4*>(T + (size_t)h * T_STRIDE + g * 64 + sl * 4) = o;
    }
}

// ---------------- launch ----------------
extern "C" void kernel_launch(void* const* d_in, const int* in_sizes, int n_in,
                              void* d_out, int out_size, void* d_ws, size_t ws_size,
                              hipStream_t stream)
{
    const float* he_feat = (const float*)d_in[0];
    const float* w1w = (const float*)d_in[4];
    const float* w1b = (const float*)d_in[5];
    const float* w2w = (const float*)d_in[6];
    const float* w2b = (const float*)d_in[7];
    const float* w6w_g[3] = {(const float*)d_in[18], (const float*)d_in[22], (const float*)d_in[26]};
    const float* w6b_g[3] = {(const float*)d_in[19], (const float*)d_in[23], (const float*)d_in[27]};
    const float* w7w_g[3] = {(const float*)d_in[20], (const float*)d_in[24], (const float*)d_in[28]};
    const float* w7b_g[3] = {(const float*)d_in[21], (const float*)d_in[25], (const float*)d_in[29]};
    const float* mlp1w = (const float*)d_in[30];
    const float* mlp1b = (const float*)d_in[31];
    const float* mlp2w = (const float*)d_in[32];
    const float* mlp2b = (const float*)d_in[33];
    const int* src_g[3] = {(const int*)d_in[34], (const int*)d_in[36], (const int*)d_in[38]};
    const int* dst_g[3] = {(const int*)d_in[35], (const int*)d_in[37], (const int*)d_in[39]};
    float* out = (float*)d_out;

    GroupPtrs Pq;
    for (int g = 0; g < 3; ++g) {
        Pq.feat[g] = (const float*)d_in[1 + g];
        Pq.wa[g] = (const float*)d_in[12 + 2 * g];
        Pq.ba[g] = (const float*)d_in[13 + 2 * g];
        Pq.wb[g] = nullptr; Pq.bb[g] = nullptr;
    }

    char* base = (char*)d_ws;
    size_t off = 0;
    auto alloc = [&](size_t bytes) {
        void* r = (void*)(base + off);
        off = (off + bytes + 255) & ~(size_t)255;
        return r;
    };
    // layout (peak ~124.2 MB):
    float* T = (float*)alloc((size_t)N_HE * T_STRIDE * 4);   // 38.4 MB, lives until mlp1
    size_t qhe_off = off;
    float* q_he = (float*)alloc((size_t)N_HE * E_DIM * 4);   // 25.6 MB, dead after R gemm
    int* ebuf = (int*)alloc((size_t)3 * E_EDGES * 4);        // 14.4 MB, dead after attn
    float* W12 = (float*)alloc(IN_F * E_DIM * 4);
    float* b12 = (float*)alloc(E_DIM * 4);
    float* q_t = (float*)alloc(N_NODES * Q_DIM * 4);
    float* B_kv = (float*)alloc(128 * R_STRIDE * 4);
    int* cnt = (int*)alloc(3 * N_HE * 4);
    int* rows = (int*)alloc(3 * (N_HE + 1) * 4);
    int* cursor = (int*)alloc(3 * N_HE * 4);
    float* R = (float*)alloc((size_t)N_HE * R_STRIDE * 4);   // 43.2 MB, dead after attn
    float* W_comp = (float*)alloc(192 * 256 * 4);            // lives until mlp1
    float* b_comp = (float*)alloc(256 * 4);
    // h1 aliases [qhe_off, qhe_off + 51.2MB): everything there is dead after attn
    float* h1 = (float*)(base + qhe_off);

    hipMemsetAsync(cnt, 0, (size_t)3 * N_HE * 4, stream);

    // weight prep
    compose_w12_kernel<<<IN_F + 1, 256, 0, stream>>>(w1w, w1b, w2w, w2b, W12, b12);
    prep_bkv_kernel<<<128, 256, 0, stream>>>(w6w_g[0], w6b_g[0], w6w_g[1], w6b_g[1],
                                             w6w_g[2], w6b_g[2], B_kv);
    prep_wcomp_kernel<<<193, 256, 0, stream>>>(w7w_g[0], w7b_g[0], w7w_g[1], w7b_g[1],
                                               w7w_g[2], w7b_g[2], mlp1w, mlp1b, W_comp, b_comp);

    // node q projection
    node_q_fused_kernel<<<N_NODES, 256, 0, stream>>>(Pq, q_t);

    // q_he = he_feat @ W12 + b12   [50000,128]
    {
        dim3 grid((N_HE + 127) / 128, E_DIM / 64);
        gemm_bias_kernel<false><<<grid, 256, 0, stream>>>(he_feat, W12, b12, q_he, N_HE, E_DIM, IN_F);
    }
    // R = q_he @ B_kv   [50000,216]
    {
        dim3 grid((N_HE + 127) / 128, (R_STRIDE + 63) / 64);
        gemm_bias_kernel<false><<<grid, 256, 0, stream>>>(q_he, B_kv, nullptr, R, N_HE, R_STRIDE, E_DIM);
    }

    // CSR build per group
    {
        int grid_e = (E_EDGES + 255) / 256;
        for (int g = 0; g < 3; ++g)
            hist_kernel<<<grid_e, 256, 0, stream>>>(src_g[g], cnt + g * N_HE, E_EDGES);
        scan_kernel<<<3, 1024, 0, stream>>>(cnt, rows, cursor);
        for (int g = 0; g < 3; ++g)
            scatter_kernel<<<grid_e, 256, 0, stream>>>(src_g[g], dst_g[g], cursor + g * N_HE,
                                                       ebuf + (size_t)g * E_EDGES, E_EDGES);
    }

    // attention on 64-dim reduced states
    attn_kernel<<<(3 * N_HE) / 4, 256, 0, stream>>>(R, q_t, rows, ebuf, T);

    // mlp1' : h1 = relu(T @ W_comp + b_comp)   [50000,256], K=192
    {
        dim3 grid1((N_HE + 127) / 128, 256 / 64);
        gemm_bias_kernel<true><<<grid1, 256, 0, stream>>>(T, W_comp, b_comp, h1, N_HE, 256, 192);
    }
    // mlp2 : out = relu(h1 @ mlp2w + mlp2b)   [50000,128]
    {
        dim3 grid2((N_HE + 127) / 128, 128 / 64);
        gemm_bias_kernel<true><<<grid2, 256, 0, stream>>>(h1, mlp2w, mlp2b, out, N_HE, 128, 256);
    }
}

// Round 7
// 817.753 us; speedup vs baseline: 1.9000x; 1.0223x over previous
//
#include <hip/hip_runtime.h>
#include <hip/hip_bf16.h>

typedef __hip_bfloat16 bf16;
typedef float f32x4 __attribute__((ext_vector_type(4)));
typedef short bf16x8s __attribute__((ext_vector_type(8)));

constexpr int N_HE = 50000;
constexpr int M_PAD = 50048;           // 391 * 128
constexpr int E_EDGES = 1200000;
constexpr int IN_F = 200;
constexpr int KP_HE = 224;             // 200 padded to x32
constexpr int HE_DIM = 512;
constexpr int E_DIM = 128;
constexpr int Q_DIM = 64;
constexpr float SCALE = 0.125f;        // 1/sqrt(64)
constexpr int N_NODES = 167 + 881 + 441; // 1489
constexpr int R_STRIDE = 216;          // 3 x 72 (64 r + 1 c + 7 pad)
constexpr int T_STRIDE = 192;          // 3 x 64
constexpr int LDSD = 40;               // LDS row stride (bf16 units): 16B-aligned frags, low conflicts

struct GroupPtrs {
    const float* feat[3];
    const float* wa[3];
    const float* ba[3];
};
struct EdgeIdx { const int* p[3]; };

__device__ __forceinline__ void split2(float v, bf16& h, bf16& l)
{
    bf16 hb = __float2bfloat16(v);
    h = hb;
    l = __float2bfloat16(v - __bfloat162float(hb));
}

// ---------------- split he_feat -> [M_PAD][224] bf16 hi/lo (rows < N_HE, k zero-padded) ----------------
__global__ __launch_bounds__(256) void split_hefeat_kernel(
    const float* __restrict__ x, bf16* __restrict__ hi, bf16* __restrict__ lo)
{
    int idx = blockIdx.x * 256 + threadIdx.x; // over N_HE*224 exactly
    int row = idx / KP_HE, k = idx - row * KP_HE;
    float v = (k < IN_F) ? x[(size_t)row * IN_F + k] : 0.f;
    bf16 h, l;
    split2(v, h, l);
    hi[idx] = h; lo[idx] = l;
}

// ---------------- compose W12 = w1_w @ w2_w -> W12t hi/lo [128][224] transposed; bias row -> b12 f32 ----------------
__global__ __launch_bounds__(256) void compose_w12_kernel(
    const float* __restrict__ w1w, const float* __restrict__ w1b,
    const float* __restrict__ w2w, const float* __restrict__ w2b,
    bf16* __restrict__ W12t_hi, bf16* __restrict__ W12t_lo, float* __restrict__ b12)
{
    int row = blockIdx.x; // 0..200
    int col = threadIdx.x & 127, ks = threadIdx.x >> 7;
    const float* a = (row < IN_F) ? (w1w + (size_t)row * HE_DIM) : w1b;
    float s = 0.f;
#pragma unroll 4
    for (int k = ks; k < HE_DIM; k += 2)
        s = fmaf(a[k], w2w[k * E_DIM + col], s);
    __shared__ float red[2][128];
    red[ks][col] = s;
    __syncthreads();
    if (ks == 0) {
        float v = red[0][col] + red[1][col];
        if (row < IN_F) {
            bf16 h, l; split2(v, h, l);
            W12t_hi[col * KP_HE + row] = h;
            W12t_lo[col * KP_HE + row] = l;
        } else b12[col] = v + w2b[col];
    }
}

// ---------------- Bt_kv hi/lo [256][128]: row c=g*72+j -> w6_g^T col / b6_g (c>=216 memset 0) ----------------
__global__ __launch_bounds__(256) void prep_bkv_kernel(
    const float* __restrict__ w6m, const float* __restrict__ b6m,
    const float* __restrict__ w6p, const float* __restrict__ b6p,
    const float* __restrict__ w6e, const float* __restrict__ b6e,
    bf16* __restrict__ Bt_hi, bf16* __restrict__ Bt_lo)
{
    int k = blockIdx.x;   // 0..127
    int c = threadIdx.x;  // 0..255
    if (c >= R_STRIDE) return;
    int g = c / 72, j = c - g * 72;
    const float* w6 = (g == 0) ? w6m : (g == 1) ? w6p : w6e;
    const float* b6 = (g == 0) ? b6m : (g == 1) ? b6p : b6e;
    float v = 0.f;
    if (j < 64) v = w6[j * E_DIM + k];
    else if (j == 64) v = b6[k];
    bf16 h, l; split2(v, h, l);
    Bt_hi[c * E_DIM + k] = h;
    Bt_lo[c * E_DIM + k] = l;
}

// ---------------- W_comp^T hi/lo [256][192] = (blockdiag(w7_g) @ mlp1_w)^T ; b_comp f32[256] ----------------
__global__ __launch_bounds__(256) void prep_wcomp_kernel(
    const float* __restrict__ w7m, const float* __restrict__ b7m,
    const float* __restrict__ w7p, const float* __restrict__ b7p,
    const float* __restrict__ w7e, const float* __restrict__ b7e,
    const float* __restrict__ mlp1w, const float* __restrict__ mlp1b,
    bf16* __restrict__ Wct_hi, bf16* __restrict__ Wct_lo, float* __restrict__ bc)
{
    int row = blockIdx.x; // 0..192 (192 = bias row)
    int n = threadIdx.x;  // 0..255
    if (row < 192) {
        int g = row >> 6, i = row & 63;
        const float* w7 = (g == 0) ? w7m : (g == 1) ? w7p : w7e;
        float s = 0.f;
#pragma unroll 4
        for (int k = 0; k < 128; ++k)
            s = fmaf(w7[i * 128 + k], mlp1w[(size_t)(g * 128 + k) * 256 + n], s);
        bf16 h, l; split2(s, h, l);
        Wct_hi[n * T_STRIDE + row] = h;
        Wct_lo[n * T_STRIDE + row] = l;
    } else {
        const float* b7s[3] = {b7m, b7p, b7e};
        float s = mlp1b[n];
        for (int g = 0; g < 3; ++g)
#pragma unroll 4
            for (int k = 0; k < 128; ++k)
                s = fmaf(b7s[g][k], mlp1w[(size_t)(g * 128 + k) * 256 + n], s);
        bc[n] = s;
    }
}

// ---------------- mlp2w^T hi/lo [128][256] ----------------
__global__ __launch_bounds__(256) void prep_m2t_kernel(
    const float* __restrict__ w, bf16* __restrict__ Wt_hi, bf16* __restrict__ Wt_lo)
{
    int n = blockIdx.x;   // 0..127
    int k = threadIdx.x;  // 0..255
    float v = w[(size_t)k * 128 + n];
    bf16 h, l; split2(v, h, l);
    Wt_hi[n * 256 + k] = h;
    Wt_lo[n * 256 + k] = l;
}

// ---------------- fused node q projection: one block per node row ----------------
__global__ __launch_bounds__(256) void node_q_fused_kernel(GroupPtrs P, float* __restrict__ qt)
{
    int b = blockIdx.x; // 0..1488
    int g = (b < 167) ? 0 : (b < 1048 ? 1 : 2);
    int row = b - (g == 0 ? 0 : (g == 1 ? 167 : 1048));
    int Dt = (g == 0) ? 167 : (g == 1 ? 881 : 441);
    const float* feat = P.feat[g] + (size_t)row * Dt;
    const float* w5 = P.wa[g];
    int col = threadIdx.x & 63, ks = threadIdx.x >> 6;
    float s = 0.f;
#pragma unroll 4
    for (int k = ks; k < Dt; k += 4)
        s = fmaf(feat[k], w5[k * Q_DIM + col], s);
    __shared__ float red[4][64];
    red[ks][col] = s;
    __syncthreads();
    if (ks == 0) {
        qt[(size_t)b * Q_DIM + col] =
            red[0][col] + red[1][col] + red[2][col] + red[3][col] + P.ba[g][col];
    }
}

// ---------------- split-precision bf16 MFMA GEMM: C = (Ah+Al)@(Bh+Bl)^T' (+bias)(relu) ----------------
// A: [M_PAD][Kp] bf16 hi/lo row-major. Bt: [Npad][Kp] bf16 hi/lo row-major (B transposed).
// 128x64 tile, 4 waves, 16x16x32 MFMA, 3 passes (hh, lh, hl). Unconditional staging (padded buffers).
template <bool BIAS, bool RELU, bool SPLIT_OUT>
__global__ __launch_bounds__(256) void mfma_gemm_kernel(
    const bf16* __restrict__ Ahg, const bf16* __restrict__ Alg, int Kp,
    const bf16* __restrict__ Bthg, const bf16* __restrict__ Btlg,
    const float* __restrict__ bias,
    float* __restrict__ Cf, bf16* __restrict__ Ch, bf16* __restrict__ Cl,
    int M, int N, int ldc)
{
    __shared__ bf16 Ah[128 * LDSD], Al[128 * LDSD], Bh[64 * LDSD], Bl[64 * LDSD];
    const int tid = threadIdx.x;
    const int bm = blockIdx.x * 128, bn = blockIdx.y * 64;
    const int lane = tid & 63, w = tid >> 6;
    const int kgrp = lane >> 4, lr = lane & 15;
    const int arow = tid >> 1, ahalf = (tid & 1) * 16;
    const int brow = tid >> 2, bq = (tid & 3) * 8;
    f32x4 acc[2][4] = {};

    for (int k0 = 0; k0 < Kp; k0 += 32) {
        // stage A 128x32 hi/lo (16 bf16 per thread each) and B 64x32 hi/lo (8 per thread each)
        {
            const size_t abase = (size_t)(bm + arow) * Kp + k0 + ahalf;
            uint4 v0 = *(const uint4*)(Ahg + abase);
            uint4 v1 = *(const uint4*)(Ahg + abase + 8);
            uint4 u0 = *(const uint4*)(Alg + abase);
            uint4 u1 = *(const uint4*)(Alg + abase + 8);
            *(uint4*)&Ah[arow * LDSD + ahalf] = v0;
            *(uint4*)&Ah[arow * LDSD + ahalf + 8] = v1;
            *(uint4*)&Al[arow * LDSD + ahalf] = u0;
            *(uint4*)&Al[arow * LDSD + ahalf + 8] = u1;
            const size_t bbase = (size_t)(bn + brow) * Kp + k0 + bq;
            uint4 w0 = *(const uint4*)(Bthg + bbase);
            uint4 w1 = *(const uint4*)(Btlg + bbase);
            *(uint4*)&Bh[brow * LDSD + bq] = w0;
            *(uint4*)&Bl[brow * LDSD + bq] = w1;
        }
        __syncthreads();
        bf16x8s afh[2], afl[2], bfh[4], bfl[4];
#pragma unroll
        for (int mi = 0; mi < 2; ++mi) {
            int r = w * 32 + mi * 16 + lr;
            afh[mi] = *(const bf16x8s*)&Ah[r * LDSD + kgrp * 8];
            afl[mi] = *(const bf16x8s*)&Al[r * LDSD + kgrp * 8];
        }
#pragma unroll
        for (int ni = 0; ni < 4; ++ni) {
            int r = ni * 16 + lr;
            bfh[ni] = *(const bf16x8s*)&Bh[r * LDSD + kgrp * 8];
            bfl[ni] = *(const bf16x8s*)&Bl[r * LDSD + kgrp * 8];
        }
#pragma unroll
        for (int mi = 0; mi < 2; ++mi)
#pragma unroll
            for (int ni = 0; ni < 4; ++ni) {
                acc[mi][ni] = __builtin_amdgcn_mfma_f32_16x16x32_bf16(afh[mi], bfh[ni], acc[mi][ni], 0, 0, 0);
                acc[mi][ni] = __builtin_amdgcn_mfma_f32_16x16x32_bf16(afl[mi], bfh[ni], acc[mi][ni], 0, 0, 0);
                acc[mi][ni] = __builtin_amdgcn_mfma_f32_16x16x32_bf16(afh[mi], bfl[ni], acc[mi][ni], 0, 0, 0);
            }
        __syncthreads();
    }

    // epilogue: D col = lane&15, row = (lane>>4)*4 + reg  [m89-verified layout]
#pragma unroll
    for (int mi = 0; mi < 2; ++mi) {
#pragma unroll
        for (int ni = 0; ni < 4; ++ni) {
            int col = bn + ni * 16 + lr;
            float bv = 0.f;
            if (BIAS) bv = (col < N) ? bias[col] : 0.f;
            int row0 = bm + w * 32 + mi * 16 + kgrp * 4;
#pragma unroll
            for (int r = 0; r < 4; ++r) {
                float v = acc[mi][ni][r] + bv;
                if (RELU) v = fmaxf(v, 0.f);
                int row = row0 + r;
                if (SPLIT_OUT) {
                    bf16 h, l; split2(v, h, l);
                    Ch[(size_t)row * ldc + col] = h;
                    Cl[(size_t)row * ldc + col] = l;
                } else {
                    if (row < M && col < N) Cf[(size_t)row * ldc + col] = v;
                }
            }
        }
    }
}

// ---------------- CSR build (merged across groups) ----------------
__global__ __launch_bounds__(256) void hist3_kernel(EdgeIdx S, int* __restrict__ cnt)
{
    int i = blockIdx.x * 256 + threadIdx.x;
    if (i >= 3 * E_EDGES) return;
    int g = i / E_EDGES, e = i - g * E_EDGES;
    atomicAdd(&cnt[g * N_HE + S.p[g][e]], 1);
}

__global__ __launch_bounds__(1024) void scan_kernel(const int* __restrict__ cnt,
                                                    int* __restrict__ rows,
                                                    int* __restrict__ cursor)
{
    int g = blockIdx.x;
    const int* c = cnt + g * N_HE;
    int* r = rows + g * (N_HE + 1);
    int* cur = cursor + g * N_HE;
    __shared__ int wsum[16];
    __shared__ int s_running;
    int tid = threadIdx.x, lane = tid & 63, w = tid >> 6;
    if (tid == 0) s_running = 0;
    __syncthreads();
    for (int base = 0; base < N_HE; base += 1024) {
        int i = base + tid;
        int v = (i < N_HE) ? c[i] : 0;
        int x = v;
#pragma unroll
        for (int off = 1; off < 64; off <<= 1) {
            int t = __shfl_up(x, off, 64);
            if (lane >= off) x += t;
        }
        if (lane == 63) wsum[w] = x;
        __syncthreads();
        if (w == 0 && lane < 16) {
            int s = wsum[lane];
#pragma unroll
            for (int off = 1; off < 16; off <<= 1) {
                int t = __shfl_up(s, off, 64);
                if (lane >= off) s += t;
            }
            wsum[lane] = s;
        }
        __syncthreads();
        int woff = (w == 0) ? 0 : wsum[w - 1];
        int total = wsum[15];
        int excl = s_running + woff + x - v;
        if (i < N_HE) { r[i] = excl; cur[i] = excl; }
        __syncthreads();
        if (tid == 0) s_running += total;
        __syncthreads();
    }
    if (tid == 0) r[N_HE] = s_running;
}

__global__ __launch_bounds__(256) void scatter3_kernel(EdgeIdx S, EdgeIdx D,
                                                       int* __restrict__ cursor, int* __restrict__ ebuf)
{
    int i = blockIdx.x * 256 + threadIdx.x;
    if (i >= 3 * E_EDGES) return;
    int g = i / E_EDGES, e = i - g * E_EDGES;
    int pos = atomicAdd(&cursor[g * N_HE + S.p[g][e]], 1);
    ebuf[(size_t)g * E_EDGES + pos] = D.p[g][e];
}

// ---------------- attention on reduced 64-dim states (writes T as split bf16) ----------------
__global__ __launch_bounds__(256) void attn_kernel(
    const float* __restrict__ R,      // [N_HE][216]
    const float* __restrict__ q_t,    // [1489][64]
    const int* __restrict__ rows_all,
    const int* __restrict__ ebuf_all,
    bf16* __restrict__ T_hi, bf16* __restrict__ T_lo) // [M_PAD][192]
{
    int wid = blockIdx.x * 4 + (threadIdx.x >> 6);
    int lane = threadIdx.x & 63;
    int g = wid / N_HE;
    int h = wid - g * N_HE;
    const int toff_tab[3] = {0, 167, 1048};
    const float* qt = q_t + (size_t)toff_tab[g] * Q_DIM;
    const int* rows = rows_all + g * (N_HE + 1);
    const int* ebuf = ebuf_all + (size_t)g * E_EDGES;
    int start = rows[h], end = rows[h + 1];

    int sub = lane >> 4, sl = lane & 15;
    const float* Rrow = R + (size_t)h * R_STRIDE + g * 72;
    float4 r4 = *reinterpret_cast<const float4*>(Rrow + sl * 4);
    float ch = Rrow[64];

    float m = -INFINITY, denom = 0.f;
    float acc0 = 0.f, acc1 = 0.f, acc2 = 0.f, acc3 = 0.f;

    for (int i0 = start + sub * 2; i0 < end; i0 += 8) {
        bool ok1 = (i0 + 1) < end;
        int d0 = ebuf[i0];
        int d1 = ebuf[ok1 ? i0 + 1 : i0];
        float4 t0 = *reinterpret_cast<const float4*>(qt + (size_t)d0 * Q_DIM + sl * 4);
        float4 t1 = *reinterpret_cast<const float4*>(qt + (size_t)d1 * Q_DIM + sl * 4);
        float p0 = t0.x * r4.x;
        p0 = fmaf(t0.y, r4.y, p0); p0 = fmaf(t0.z, r4.z, p0); p0 = fmaf(t0.w, r4.w, p0);
        float p1 = t1.x * r4.x;
        p1 = fmaf(t1.y, r4.y, p1); p1 = fmaf(t1.z, r4.z, p1); p1 = fmaf(t1.w, r4.w, p1);
#pragma unroll
        for (int mask = 1; mask < 16; mask <<= 1) {
            p0 += __shfl_xor(p0, mask, 64);
            p1 += __shfl_xor(p1, mask, 64);
        }
        float s0 = (p0 + ch) * SCALE; s0 = s0 > 0.f ? s0 : 0.01f * s0;
        float s1 = (p1 + ch) * SCALE; s1 = s1 > 0.f ? s1 : 0.01f * s1;
        if (!ok1) s1 = -INFINITY;
        float newm = fmaxf(fmaxf(s0, s1), m);
        float sc = __expf(m - newm);
        float w0 = __expf(s0 - newm);
        float w1 = __expf(s1 - newm);
        denom = fmaf(denom, sc, w0 + w1);
        acc0 = fmaf(w0, t0.x, fmaf(w1, t1.x, acc0 * sc));
        acc1 = fmaf(w0, t0.y, fmaf(w1, t1.y, acc1 * sc));
        acc2 = fmaf(w0, t0.z, fmaf(w1, t1.z, acc2 * sc));
        acc3 = fmaf(w0, t0.w, fmaf(w1, t1.w, acc3 * sc));
        m = newm;
    }

    float om = fmaxf(m, __shfl_xor(m, 16, 64));
    om = fmaxf(om, __shfl_xor(om, 32, 64));
    float f = (denom > 0.f) ? __expf(m - om) : 0.f;
    float d = denom * f;
    d += __shfl_xor(d, 16, 64);
    d += __shfl_xor(d, 32, 64);
    float a0 = acc0 * f, a1 = acc1 * f, a2 = acc2 * f, a3 = acc3 * f;
    a0 += __shfl_xor(a0, 16, 64); a0 += __shfl_xor(a0, 32, 64);
    a1 += __shfl_xor(a1, 16, 64); a1 += __shfl_xor(a1, 32, 64);
    a2 += __shfl_xor(a2, 16, 64); a2 += __shfl_xor(a2, 32, 64);
    a3 += __shfl_xor(a3, 16, 64); a3 += __shfl_xor(a3, 32, 64);
    if (sub == 0) {
        float rden = 1.f / fmaxf(d, 1e-20f);
        float o[4] = {a0 * rden, a1 * rden, a2 * rden, a3 * rden};
        size_t bix = (size_t)h * T_STRIDE + g * 64 + sl * 4;
#pragma unroll
        for (int e = 0; e < 4; ++e) {
            bf16 hh, ll; split2(o[e], hh, ll);
            T_hi[bix + e] = hh;
            T_lo[bix + e] = ll;
        }
    }
}

// ---------------- launch ----------------
extern "C" void kernel_launch(void* const* d_in, const int* in_sizes, int n_in,
                              void* d_out, int out_size, void* d_ws, size_t ws_size,
                              hipStream_t stream)
{
    const float* he_feat = (const float*)d_in[0];
    const float* w1w = (const float*)d_in[4];
    const float* w1b = (const float*)d_in[5];
    const float* w2w = (const float*)d_in[6];
    const float* w2b = (const float*)d_in[7];
    const float* w6w_g[3] = {(const float*)d_in[18], (const float*)d_in[22], (const float*)d_in[26]};
    const float* w6b_g[3] = {(const float*)d_in[19], (const float*)d_in[23], (const float*)d_in[27]};
    const float* w7w_g[3] = {(const float*)d_in[20], (const float*)d_in[24], (const float*)d_in[28]};
    const float* w7b_g[3] = {(const float*)d_in[21], (const float*)d_in[25], (const float*)d_in[29]};
    const float* mlp1w = (const float*)d_in[30];
    const float* mlp1b = (const float*)d_in[31];
    const float* mlp2w = (const float*)d_in[32];
    const float* mlp2b = (const float*)d_in[33];
    float* out = (float*)d_out;

    GroupPtrs Pq;
    for (int g = 0; g < 3; ++g) {
        Pq.feat[g] = (const float*)d_in[1 + g];
        Pq.wa[g] = (const float*)d_in[12 + 2 * g];
        Pq.ba[g] = (const float*)d_in[13 + 2 * g];
    }
    EdgeIdx Esrc, Edst;
    for (int g = 0; g < 3; ++g) {
        Esrc.p[g] = (const int*)d_in[34 + 2 * g];
        Edst.p[g] = (const int*)d_in[35 + 2 * g];
    }

    char* base = (char*)d_ws;
    size_t off = 0;
    auto alloc = [&](size_t bytes) -> void* {
        void* r = (void*)(base + off);
        off = (off + bytes + 255) & ~(size_t)255;
        return r;
    };
    // ---- persistent small region ----
    bf16* W12t_hi = (bf16*)alloc(128 * KP_HE * 2);  // 57344 (contiguous memset block start)
    bf16* W12t_lo = (bf16*)alloc(128 * KP_HE * 2);
    bf16* Btkv_hi = (bf16*)alloc(256 * E_DIM * 2);  // 65536
    bf16* Btkv_lo = (bf16*)alloc(256 * E_DIM * 2);  // memset block end (245760 B total)
    float* b12 = (float*)alloc(128 * 4);
    bf16* Wct_hi = (bf16*)alloc(256 * T_STRIDE * 2);
    bf16* Wct_lo = (bf16*)alloc(256 * T_STRIDE * 2);
    float* b_comp = (float*)alloc(256 * 4);
    bf16* Wm2t_hi = (bf16*)alloc(128 * 256 * 2);
    bf16* Wm2t_lo = (bf16*)alloc(128 * 256 * 2);
    float* q_t = (float*)alloc(N_NODES * Q_DIM * 4);
    int* cnt = (int*)alloc(3 * N_HE * 4);
    int* rows = (int*)alloc(3 * (N_HE + 1) * 4);
    int* cursor = (int*)alloc(3 * N_HE * 4);
    // ---- big buffers with lifetime overlays ----
    size_t T_start = off;
    bf16* T_hi = (bf16*)alloc((size_t)M_PAD * T_STRIDE * 2);   // 19.2 MB  [attn -> mlp1]
    bf16* T_lo = (bf16*)alloc((size_t)M_PAD * T_STRIDE * 2);
    size_t R_start = off;
    float* R = (float*)alloc((size_t)N_HE * R_STRIDE * 4);     // 43.2 MB  [R-gemm -> attn]
    int* ebuf = (int*)alloc((size_t)3 * E_EDGES * 4);          // 14.4 MB  [scatter -> attn]
    bf16* qhe_hi = (bf16*)alloc((size_t)M_PAD * E_DIM * 2);    // 12.8 MB  [q_he gemm -> R gemm]
    bf16* qhe_lo = (bf16*)alloc((size_t)M_PAD * E_DIM * 2);
    // he_split (44.8 MB, phase A only): overlays T (+6.4MB of R head) — both written later.
    bf16* he_hi = (bf16*)(base + T_start);
    bf16* he_lo = he_hi + (size_t)M_PAD * KP_HE;
    // h1 (51.2 MB, mlp1 -> mlp2): overlays R + ebuf (dead after attn).
    bf16* h1_hi = (bf16*)(base + R_start);
    bf16* h1_lo = h1_hi + (size_t)M_PAD * 256;

    hipMemsetAsync(cnt, 0, (size_t)3 * N_HE * 4, stream);
    hipMemsetAsync(W12t_hi, 0, 245760, stream); // zero-pads W12t + Btkv (hi & lo)

    // phase A: splits, CSR, weight prep, node q
    split_hefeat_kernel<<<(N_HE * KP_HE) / 256, 256, 0, stream>>>(he_feat, he_hi, he_lo);
    hist3_kernel<<<(3 * E_EDGES + 255) / 256, 256, 0, stream>>>(Esrc, cnt);
    scan_kernel<<<3, 1024, 0, stream>>>(cnt, rows, cursor);
    scatter3_kernel<<<(3 * E_EDGES + 255) / 256, 256, 0, stream>>>(Esrc, Edst, cursor, ebuf);
    compose_w12_kernel<<<IN_F + 1, 256, 0, stream>>>(w1w, w1b, w2w, w2b, W12t_hi, W12t_lo, b12);
    prep_bkv_kernel<<<128, 256, 0, stream>>>(w6w_g[0], w6b_g[0], w6w_g[1], w6b_g[1],
                                             w6w_g[2], w6b_g[2], Btkv_hi, Btkv_lo);
    prep_wcomp_kernel<<<193, 256, 0, stream>>>(w7w_g[0], w7b_g[0], w7w_g[1], w7b_g[1],
                                               w7w_g[2], w7b_g[2], mlp1w, mlp1b, Wct_hi, Wct_lo, b_comp);
    prep_m2t_kernel<<<128, 256, 0, stream>>>(mlp2w, Wm2t_hi, Wm2t_lo);
    node_q_fused_kernel<<<N_NODES, 256, 0, stream>>>(Pq, q_t);

    const int MB = M_PAD / 128; // 391
    // q_he = he_feat @ W12 + b12 -> split [M_PAD][128]
    mfma_gemm_kernel<true, false, true><<<dim3(MB, 2), 256, 0, stream>>>(
        he_hi, he_lo, KP_HE, W12t_hi, W12t_lo, b12, nullptr, qhe_hi, qhe_lo, N_HE, E_DIM, E_DIM);
    // R = q_he @ B_kv -> f32 [N_HE][216]
    mfma_gemm_kernel<false, false, false><<<dim3(MB, 4), 256, 0, stream>>>(
        qhe_hi, qhe_lo, E_DIM, Btkv_hi, Btkv_lo, nullptr, R, nullptr, nullptr, N_HE, R_STRIDE, R_STRIDE);
    // attention -> T split [M_PAD][192]
    attn_kernel<<<(3 * N_HE) / 4, 256, 0, stream>>>(R, q_t, rows, ebuf, T_hi, T_lo);
    // h1 = relu(T @ W_comp + b_comp) -> split [M_PAD][256]
    mfma_gemm_kernel<true, true, true><<<dim3(MB, 4), 256, 0, stream>>>(
        T_hi, T_lo, T_STRIDE, Wct_hi, Wct_lo, b_comp, nullptr, h1_hi, h1_lo, N_HE, 256, 256);
    // out = relu(h1 @ mlp2w + mlp2b) -> f32 [N_HE][128]
    mfma_gemm_kernel<true, true, false><<<dim3(MB, 2), 256, 0, stream>>>(
        h1_hi, h1_lo, 256, Wm2t_hi, Wm2t_lo, mlp2b, out, nullptr, nullptr, N_HE, E_DIM, E_DIM);
}

// Round 8
// 398.552 us; speedup vs baseline: 3.8984x; 2.0518x over previous
//
#include <hip/hip_runtime.h>
#include <hip/hip_bf16.h>

typedef __hip_bfloat16 bf16;
typedef float f32x4 __attribute__((ext_vector_type(4)));
typedef short bf16x8s __attribute__((ext_vector_type(8)));

constexpr int N_HE = 50000;
constexpr int M_PAD = 50048;           // 391 * 128
constexpr int E_EDGES = 1200000;
constexpr int IN_F = 200;
constexpr int KP_HE = 224;             // 200 padded to x32
constexpr int HE_DIM = 512;
constexpr int E_DIM = 128;
constexpr int Q_DIM = 64;
constexpr float SCALE = 0.125f;        // 1/sqrt(64)
constexpr int N_NODES = 167 + 881 + 441; // 1489
constexpr int R_STRIDE = 216;          // 3 x 72 (64 r + 1 c + 7 pad)
constexpr int T_STRIDE = 192;          // 3 x 64
constexpr int LDSD = 40;               // LDS row stride (bf16) for GEMM staging
constexpr int NBIN = 98;               // ceil(50000/512) bins per group
constexpr int BIN_SHIFT = 9;           // 512 hyperedges per bin
constexpr int ECHUNK = 4096;           // edges per bin_scatter block

struct GroupPtrs {
    const float* feat[3];
    const float* wa[3];
    const float* ba[3];
};
struct EdgeIdx { const int* p[3]; };

__device__ __forceinline__ void split2(float v, bf16& h, bf16& l)
{
    bf16 hb = __float2bfloat16(v);
    h = hb;
    l = __float2bfloat16(v - __bfloat162float(hb));
}

// ---------------- split he_feat -> [M_PAD][224] bf16 hi/lo ----------------
__global__ __launch_bounds__(256) void split_hefeat_kernel(
    const float* __restrict__ x, bf16* __restrict__ hi, bf16* __restrict__ lo)
{
    int idx = blockIdx.x * 256 + threadIdx.x; // over N_HE*224 exactly
    int row = idx / KP_HE, k = idx - row * KP_HE;
    float v = (k < IN_F) ? x[(size_t)row * IN_F + k] : 0.f;
    bf16 h, l;
    split2(v, h, l);
    hi[idx] = h; lo[idx] = l;
}

// ---------------- compose W12 -> W12t hi/lo [128][224]; bias -> b12 ----------------
__global__ __launch_bounds__(256) void compose_w12_kernel(
    const float* __restrict__ w1w, const float* __restrict__ w1b,
    const float* __restrict__ w2w, const float* __restrict__ w2b,
    bf16* __restrict__ W12t_hi, bf16* __restrict__ W12t_lo, float* __restrict__ b12)
{
    int row = blockIdx.x; // 0..200
    int col = threadIdx.x & 127, ks = threadIdx.x >> 7;
    const float* a = (row < IN_F) ? (w1w + (size_t)row * HE_DIM) : w1b;
    float s = 0.f;
#pragma unroll 4
    for (int k = ks; k < HE_DIM; k += 2)
        s = fmaf(a[k], w2w[k * E_DIM + col], s);
    __shared__ float red[2][128];
    red[ks][col] = s;
    __syncthreads();
    if (ks == 0) {
        float v = red[0][col] + red[1][col];
        if (row < IN_F) {
            bf16 h, l; split2(v, h, l);
            W12t_hi[col * KP_HE + row] = h;
            W12t_lo[col * KP_HE + row] = l;
        } else b12[col] = v + w2b[col];
    }
}

// ---------------- Bt_kv hi/lo [256][128] ----------------
__global__ __launch_bounds__(256) void prep_bkv_kernel(
    const float* __restrict__ w6m, const float* __restrict__ b6m,
    const float* __restrict__ w6p, const float* __restrict__ b6p,
    const float* __restrict__ w6e, const float* __restrict__ b6e,
    bf16* __restrict__ Bt_hi, bf16* __restrict__ Bt_lo)
{
    int k = blockIdx.x;   // 0..127
    int c = threadIdx.x;  // 0..255
    if (c >= R_STRIDE) return;
    int g = c / 72, j = c - g * 72;
    const float* w6 = (g == 0) ? w6m : (g == 1) ? w6p : w6e;
    const float* b6 = (g == 0) ? b6m : (g == 1) ? b6p : b6e;
    float v = 0.f;
    if (j < 64) v = w6[j * E_DIM + k];
    else if (j == 64) v = b6[k];
    bf16 h, l; split2(v, h, l);
    Bt_hi[c * E_DIM + k] = h;
    Bt_lo[c * E_DIM + k] = l;
}

// ---------------- W_comp^T hi/lo [256][192]; b_comp f32[256] ----------------
__global__ __launch_bounds__(256) void prep_wcomp_kernel(
    const float* __restrict__ w7m, const float* __restrict__ b7m,
    const float* __restrict__ w7p, const float* __restrict__ b7p,
    const float* __restrict__ w7e, const float* __restrict__ b7e,
    const float* __restrict__ mlp1w, const float* __restrict__ mlp1b,
    bf16* __restrict__ Wct_hi, bf16* __restrict__ Wct_lo, float* __restrict__ bc)
{
    int row = blockIdx.x; // 0..192 (192 = bias row)
    int n = threadIdx.x;  // 0..255
    if (row < 192) {
        int g = row >> 6, i = row & 63;
        const float* w7 = (g == 0) ? w7m : (g == 1) ? w7p : w7e;
        float s = 0.f;
#pragma unroll 4
        for (int k = 0; k < 128; ++k)
            s = fmaf(w7[i * 128 + k], mlp1w[(size_t)(g * 128 + k) * 256 + n], s);
        bf16 h, l; split2(s, h, l);
        Wct_hi[n * T_STRIDE + row] = h;
        Wct_lo[n * T_STRIDE + row] = l;
    } else {
        const float* b7s[3] = {b7m, b7p, b7e};
        float s = mlp1b[n];
        for (int g = 0; g < 3; ++g)
#pragma unroll 4
            for (int k = 0; k < 128; ++k)
                s = fmaf(b7s[g][k], mlp1w[(size_t)(g * 128 + k) * 256 + n], s);
        bc[n] = s;
    }
}

// ---------------- mlp2w^T hi/lo [128][256] ----------------
__global__ __launch_bounds__(256) void prep_m2t_kernel(
    const float* __restrict__ w, bf16* __restrict__ Wt_hi, bf16* __restrict__ Wt_lo)
{
    int n = blockIdx.x;   // 0..127
    int k = threadIdx.x;  // 0..255
    float v = w[(size_t)k * 128 + n];
    bf16 h, l; split2(v, h, l);
    Wt_hi[n * 256 + k] = h;
    Wt_lo[n * 256 + k] = l;
}

// ---------------- fused node q projection ----------------
__global__ __launch_bounds__(256) void node_q_fused_kernel(GroupPtrs P, float* __restrict__ qt)
{
    int b = blockIdx.x; // 0..1488
    int g = (b < 167) ? 0 : (b < 1048 ? 1 : 2);
    int row = b - (g == 0 ? 0 : (g == 1 ? 167 : 1048));
    int Dt = (g == 0) ? 167 : (g == 1 ? 881 : 441);
    const float* feat = P.feat[g] + (size_t)row * Dt;
    const float* w5 = P.wa[g];
    int col = threadIdx.x & 63, ks = threadIdx.x >> 6;
    float s = 0.f;
#pragma unroll 4
    for (int k = ks; k < Dt; k += 4)
        s = fmaf(feat[k], w5[k * Q_DIM + col], s);
    __shared__ float red[4][64];
    red[ks][col] = s;
    __syncthreads();
    if (ks == 0) {
        qt[(size_t)b * Q_DIM + col] =
            red[0][col] + red[1][col] + red[2][col] + red[3][col] + P.ba[g][col];
    }
}

// ---------------- split-precision bf16 MFMA GEMM ----------------
template <bool BIAS, bool RELU, bool SPLIT_OUT>
__global__ __launch_bounds__(256) void mfma_gemm_kernel(
    const bf16* __restrict__ Ahg, const bf16* __restrict__ Alg, int Kp,
    const bf16* __restrict__ Bthg, const bf16* __restrict__ Btlg,
    const float* __restrict__ bias,
    float* __restrict__ Cf, bf16* __restrict__ Ch, bf16* __restrict__ Cl,
    int M, int N, int ldc)
{
    __shared__ bf16 Ah[128 * LDSD], Al[128 * LDSD], Bh[64 * LDSD], Bl[64 * LDSD];
    const int tid = threadIdx.x;
    const int bm = blockIdx.x * 128, bn = blockIdx.y * 64;
    const int lane = tid & 63, w = tid >> 6;
    const int kgrp = lane >> 4, lr = lane & 15;
    const int arow = tid >> 1, ahalf = (tid & 1) * 16;
    const int brow = tid >> 2, bq = (tid & 3) * 8;
    f32x4 acc[2][4] = {};

    for (int k0 = 0; k0 < Kp; k0 += 32) {
        {
            const size_t abase = (size_t)(bm + arow) * Kp + k0 + ahalf;
            uint4 v0 = *(const uint4*)(Ahg + abase);
            uint4 v1 = *(const uint4*)(Ahg + abase + 8);
            uint4 u0 = *(const uint4*)(Alg + abase);
            uint4 u1 = *(const uint4*)(Alg + abase + 8);
            *(uint4*)&Ah[arow * LDSD + ahalf] = v0;
            *(uint4*)&Ah[arow * LDSD + ahalf + 8] = v1;
            *(uint4*)&Al[arow * LDSD + ahalf] = u0;
            *(uint4*)&Al[arow * LDSD + ahalf + 8] = u1;
            const size_t bbase = (size_t)(bn + brow) * Kp + k0 + bq;
            uint4 w0 = *(const uint4*)(Bthg + bbase);
            uint4 w1 = *(const uint4*)(Btlg + bbase);
            *(uint4*)&Bh[brow * LDSD + bq] = w0;
            *(uint4*)&Bl[brow * LDSD + bq] = w1;
        }
        __syncthreads();
        bf16x8s afh[2], afl[2], bfh[4], bfl[4];
#pragma unroll
        for (int mi = 0; mi < 2; ++mi) {
            int r = w * 32 + mi * 16 + lr;
            afh[mi] = *(const bf16x8s*)&Ah[r * LDSD + kgrp * 8];
            afl[mi] = *(const bf16x8s*)&Al[r * LDSD + kgrp * 8];
        }
#pragma unroll
        for (int ni = 0; ni < 4; ++ni) {
            int r = ni * 16 + lr;
            bfh[ni] = *(const bf16x8s*)&Bh[r * LDSD + kgrp * 8];
            bfl[ni] = *(const bf16x8s*)&Bl[r * LDSD + kgrp * 8];
        }
#pragma unroll
        for (int mi = 0; mi < 2; ++mi)
#pragma unroll
            for (int ni = 0; ni < 4; ++ni) {
                acc[mi][ni] = __builtin_amdgcn_mfma_f32_16x16x32_bf16(afh[mi], bfh[ni], acc[mi][ni], 0, 0, 0);
                acc[mi][ni] = __builtin_amdgcn_mfma_f32_16x16x32_bf16(afl[mi], bfh[ni], acc[mi][ni], 0, 0, 0);
                acc[mi][ni] = __builtin_amdgcn_mfma_f32_16x16x32_bf16(afh[mi], bfl[ni], acc[mi][ni], 0, 0, 0);
            }
        __syncthreads();
    }

#pragma unroll
    for (int mi = 0; mi < 2; ++mi) {
#pragma unroll
        for (int ni = 0; ni < 4; ++ni) {
            int col = bn + ni * 16 + lr;
            float bv = 0.f;
            if (BIAS) bv = (col < N) ? bias[col] : 0.f;
            int row0 = bm + w * 32 + mi * 16 + kgrp * 4;
#pragma unroll
            for (int r = 0; r < 4; ++r) {
                float v = acc[mi][ni][r] + bv;
                if (RELU) v = fmaxf(v, 0.f);
                int row = row0 + r;
                if (SPLIT_OUT) {
                    bf16 h, l; split2(v, h, l);
                    Ch[(size_t)row * ldc + col] = h;
                    Cl[(size_t)row * ldc + col] = l;
                } else {
                    if (row < M && col < N) Cf[(size_t)row * ldc + col] = v;
                }
            }
        }
    }
}

// ================= binned CSR build =================
// coarse histogram: 98 bins per group, LDS-aggregated
__global__ __launch_bounds__(256) void coarse_hist3_kernel(EdgeIdx S, int* __restrict__ bincnt)
{
    int g = blockIdx.y;
    const int* src = S.p[g];
    __shared__ int h[NBIN];
    int tid = threadIdx.x;
    if (tid < NBIN) h[tid] = 0;
    __syncthreads();
    int base = blockIdx.x * ECHUNK;
#pragma unroll
    for (int k = 0; k < ECHUNK / 256; ++k) {
        int i = base + k * 256 + tid;
        if (i < E_EDGES) atomicAdd(&h[src[i] >> BIN_SHIFT], 1);
    }
    __syncthreads();
    if (tid < NBIN && h[tid]) atomicAdd(&bincnt[g * NBIN + tid], h[tid]);
}

// one block: per-group exclusive scan of 98 bins -> binoff[3][99], init bincursor
__global__ __launch_bounds__(192) void coarse_scan_kernel(
    const int* __restrict__ bincnt, int* __restrict__ binoff, int* __restrict__ bincursor)
{
    int lane = threadIdx.x & 63, g = threadIdx.x >> 6; // 3 waves, one per group
    int v0 = (lane < NBIN) ? bincnt[g * NBIN + lane] : 0;
    int v1 = (64 + lane < NBIN) ? bincnt[g * NBIN + 64 + lane] : 0;
    int x0 = v0, x1 = v1;
#pragma unroll
    for (int o = 1; o < 64; o <<= 1) {
        int t0 = __shfl_up(x0, o, 64);
        int t1 = __shfl_up(x1, o, 64);
        if (lane >= o) { x0 += t0; x1 += t1; }
    }
    int tot0 = __shfl(x0, 63, 64);
    if (lane < NBIN) {
        int e = x0 - v0;
        binoff[g * (NBIN + 1) + lane] = e;
        bincursor[g * NBIN + lane] = e;
    }
    if (64 + lane < NBIN) {
        int e = tot0 + x1 - v1;
        binoff[g * (NBIN + 1) + 64 + lane] = e;
        bincursor[g * NBIN + 64 + lane] = e;
    }
    if (lane == 63) binoff[g * (NBIN + 1) + NBIN] = tot0 + x1; // == E_EDGES
}

// bin edges: LDS sort by bin, reserve per-(block,bin) space, coalesced copy-out
__global__ __launch_bounds__(256) void bin_scatter_kernel(
    EdgeIdx S, EdgeIdx D, int* __restrict__ bincursor, unsigned* __restrict__ binbuf)
{
    int g = blockIdx.y;
    const int* src = S.p[g];
    const int* dst = D.p[g];
    __shared__ unsigned stage[ECHUNK];
    __shared__ int hist[NBIN], off[NBIN], cur[NBIN], gbase[NBIN];
    int tid = threadIdx.x, lane = tid & 63, w = tid >> 6;
    if (tid < NBIN) hist[tid] = 0;
    __syncthreads();

    int base = blockIdx.x * ECHUNK;
    int s[ECHUNK / 256], d[ECHUNK / 256];
#pragma unroll
    for (int k = 0; k < ECHUNK / 256; ++k) {
        int i = base + k * 256 + tid;
        if (i < E_EDGES) {
            s[k] = src[i];
            d[k] = dst[i];
            atomicAdd(&hist[s[k] >> BIN_SHIFT], 1);
        } else s[k] = -1;
    }
    __syncthreads();
    // wave-0 scan of 98 bins
    if (w == 0) {
        int v0 = (lane < NBIN) ? hist[lane] : 0;
        int v1 = (64 + lane < NBIN) ? hist[64 + lane] : 0;
        int x0 = v0, x1 = v1;
#pragma unroll
        for (int o = 1; o < 64; o <<= 1) {
            int t0 = __shfl_up(x0, o, 64);
            int t1 = __shfl_up(x1, o, 64);
            if (lane >= o) { x0 += t0; x1 += t1; }
        }
        int tot0 = __shfl(x0, 63, 64);
        if (lane < NBIN) { off[lane] = x0 - v0; cur[lane] = x0 - v0; }
        if (64 + lane < NBIN) { off[64 + lane] = tot0 + x1 - v1; cur[64 + lane] = tot0 + x1 - v1; }
    }
    __syncthreads();
    if (tid < NBIN) gbase[tid] = atomicAdd(&bincursor[g * NBIN + tid], hist[tid]);
    __syncthreads();
#pragma unroll
    for (int k = 0; k < ECHUNK / 256; ++k) {
        if (s[k] >= 0) {
            int bin = s[k] >> BIN_SHIFT;
            int pos = atomicAdd(&cur[bin], 1);
            stage[pos] = ((unsigned)(s[k] & 511) << 10) | (unsigned)d[k];
        }
    }
    __syncthreads();
    // copy out: wave w handles bins w, w+4, ...
    size_t gE = (size_t)g * E_EDGES;
    for (int b = w; b < NBIN; b += 4) {
        int len = hist[b], lo = off[b], gb = gbase[b];
        for (int j = lane; j < len; j += 64)
            binbuf[gE + gb + j] = stage[lo + j];
    }
}

// per-bin CSR: LDS 512-hist + scan -> rows; localized scatter -> ebuf
__global__ __launch_bounds__(256) void bin_csr_kernel(
    const unsigned* __restrict__ binbuf, const int* __restrict__ binoff,
    int* __restrict__ rows_all, int* __restrict__ ebuf)
{
    int b = blockIdx.x, g = blockIdx.y;
    int start = binoff[g * (NBIN + 1) + b];
    int end = binoff[g * (NBIN + 1) + b + 1];
    int h0 = b << BIN_SHIFT;
    int hN = min(512, N_HE - h0);
    size_t gE = (size_t)g * E_EDGES;
    int* rows = rows_all + g * (N_HE + 1);
    __shared__ int hist[512], cur[512], cs[8];
    int tid = threadIdx.x, lane = tid & 63, w = tid >> 6;
    hist[tid] = 0; hist[tid + 256] = 0;
    __syncthreads();
    for (int i = start + tid; i < end; i += 256)
        atomicAdd(&hist[binbuf[gE + i] >> 10], 1);
    __syncthreads();
    // scan 512 = 8 chunks of 64; wave w owns chunks 2w, 2w+1
#pragma unroll
    for (int c2 = 0; c2 < 2; ++c2) {
        int c = w * 2 + c2, idx = c * 64 + lane;
        int v = hist[idx], x = v;
#pragma unroll
        for (int o = 1; o < 64; o <<= 1) {
            int t = __shfl_up(x, o, 64);
            if (lane >= o) x += t;
        }
        cur[idx] = x - v;
        if (lane == 63) cs[c] = x;
    }
    __syncthreads();
    if (tid == 0) {
        int run = 0;
#pragma unroll
        for (int c = 0; c < 8; ++c) { int t = cs[c]; cs[c] = run; run += t; }
    }
    __syncthreads();
#pragma unroll
    for (int c2 = 0; c2 < 2; ++c2) {
        int c = w * 2 + c2, idx = c * 64 + lane;
        int e = cur[idx] + cs[c];
        cur[idx] = e;
        if (idx < hN) rows[h0 + idx] = start + e;
    }
    if (b == NBIN - 1 && tid == 0) rows[N_HE] = end; // == E_EDGES
    __syncthreads();
    for (int i = start + tid; i < end; i += 256) {
        unsigned p = binbuf[gE + i];
        int pos = atomicAdd(&cur[p >> 10], 1);
        ebuf[gE + start + pos] = (int)(p & 1023u);
    }
}

// ---------------- attention on reduced 64-dim states ----------------
__global__ __launch_bounds__(256) void attn_kernel(
    const float* __restrict__ R,      // [N_HE][216]
    const float* __restrict__ q_t,    // [1489][64]
    const int* __restrict__ rows_all,
    const int* __restrict__ ebuf_all,
    bf16* __restrict__ T_hi, bf16* __restrict__ T_lo) // [M_PAD][192]
{
    int wid = blockIdx.x * 4 + (threadIdx.x >> 6);
    int lane = threadIdx.x & 63;
    int g = wid / N_HE;
    int h = wid - g * N_HE;
    const int toff_tab[3] = {0, 167, 1048};
    const float* qt = q_t + (size_t)toff_tab[g] * Q_DIM;
    const int* rows = rows_all + g * (N_HE + 1);
    const int* ebuf = ebuf_all + (size_t)g * E_EDGES;
    int start = rows[h], end = rows[h + 1];

    int sub = lane >> 4, sl = lane & 15;
    const float* Rrow = R + (size_t)h * R_STRIDE + g * 72;
    float4 r4 = *reinterpret_cast<const float4*>(Rrow + sl * 4);
    float ch = Rrow[64];

    float m = -INFINITY, denom = 0.f;
    float acc0 = 0.f, acc1 = 0.f, acc2 = 0.f, acc3 = 0.f;

    for (int i0 = start + sub * 2; i0 < end; i0 += 8) {
        bool ok1 = (i0 + 1) < end;
        int d0 = ebuf[i0];
        int d1 = ebuf[ok1 ? i0 + 1 : i0];
        float4 t0 = *reinterpret_cast<const float4*>(qt + (size_t)d0 * Q_DIM + sl * 4);
        float4 t1 = *reinterpret_cast<const float4*>(qt + (size_t)d1 * Q_DIM + sl * 4);
        float p0 = t0.x * r4.x;
        p0 = fmaf(t0.y, r4.y, p0); p0 = fmaf(t0.z, r4.z, p0); p0 = fmaf(t0.w, r4.w, p0);
        float p1 = t1.x * r4.x;
        p1 = fmaf(t1.y, r4.y, p1); p1 = fmaf(t1.z, r4.z, p1); p1 = fmaf(t1.w, r4.w, p1);
#pragma unroll
        for (int mask = 1; mask < 16; mask <<= 1) {
            p0 += __shfl_xor(p0, mask, 64);
            p1 += __shfl_xor(p1, mask, 64);
        }
        float s0 = (p0 + ch) * SCALE; s0 = s0 > 0.f ? s0 : 0.01f * s0;
        float s1 = (p1 + ch) * SCALE; s1 = s1 > 0.f ? s1 : 0.01f * s1;
        if (!ok1) s1 = -INFINITY;
        float newm = fmaxf(fmaxf(s0, s1), m);
        float sc = __expf(m - newm);
        float w0 = __expf(s0 - newm);
        float w1 = __expf(s1 - newm);
        denom = fmaf(denom, sc, w0 + w1);
        acc0 = fmaf(w0, t0.x, fmaf(w1, t1.x, acc0 * sc));
        acc1 = fmaf(w0, t0.y, fmaf(w1, t1.y, acc1 * sc));
        acc2 = fmaf(w0, t0.z, fmaf(w1, t1.z, acc2 * sc));
        acc3 = fmaf(w0, t0.w, fmaf(w1, t1.w, acc3 * sc));
        m = newm;
    }

    float om = fmaxf(m, __shfl_xor(m, 16, 64));
    om = fmaxf(om, __shfl_xor(om, 32, 64));
    float f = (denom > 0.f) ? __expf(m - om) : 0.f;
    float d = denom * f;
    d += __shfl_xor(d, 16, 64);
    d += __shfl_xor(d, 32, 64);
    float a0 = acc0 * f, a1 = acc1 * f, a2 = acc2 * f, a3 = acc3 * f;
    a0 += __shfl_xor(a0, 16, 64); a0 += __shfl_xor(a0, 32, 64);
    a1 += __shfl_xor(a1, 16, 64); a1 += __shfl_xor(a1, 32, 64);
    a2 += __shfl_xor(a2, 16, 64); a2 += __shfl_xor(a2, 32, 64);
    a3 += __shfl_xor(a3, 16, 64); a3 += __shfl_xor(a3, 32, 64);
    if (sub == 0) {
        float rden = 1.f / fmaxf(d, 1e-20f);
        float o[4] = {a0 * rden, a1 * rden, a2 * rden, a3 * rden};
        size_t bix = (size_t)h * T_STRIDE + g * 64 + sl * 4;
#pragma unroll
        for (int e = 0; e < 4; ++e) {
            bf16 hh, ll; split2(o[e], hh, ll);
            T_hi[bix + e] = hh;
            T_lo[bix + e] = ll;
        }
    }
}

// ---------------- launch ----------------
extern "C" void kernel_launch(void* const* d_in, const int* in_sizes, int n_in,
                              void* d_out, int out_size, void* d_ws, size_t ws_size,
                              hipStream_t stream)
{
    const float* he_feat = (const float*)d_in[0];
    const float* w1w = (const float*)d_in[4];
    const float* w1b = (const float*)d_in[5];
    const float* w2w = (const float*)d_in[6];
    const float* w2b = (const float*)d_in[7];
    const float* w6w_g[3] = {(const float*)d_in[18], (const float*)d_in[22], (const float*)d_in[26]};
    const float* w6b_g[3] = {(const float*)d_in[19], (const float*)d_in[23], (const float*)d_in[27]};
    const float* w7w_g[3] = {(const float*)d_in[20], (const float*)d_in[24], (const float*)d_in[28]};
    const float* w7b_g[3] = {(const float*)d_in[21], (const float*)d_in[25], (const float*)d_in[29]};
    const float* mlp1w = (const float*)d_in[30];
    const float* mlp1b = (const float*)d_in[31];
    const float* mlp2w = (const float*)d_in[32];
    const float* mlp2b = (const float*)d_in[33];
    float* out = (float*)d_out;

    GroupPtrs Pq;
    for (int g = 0; g < 3; ++g) {
        Pq.feat[g] = (const float*)d_in[1 + g];
        Pq.wa[g] = (const float*)d_in[12 + 2 * g];
        Pq.ba[g] = (const float*)d_in[13 + 2 * g];
    }
    EdgeIdx Esrc, Edst;
    for (int g = 0; g < 3; ++g) {
        Esrc.p[g] = (const int*)d_in[34 + 2 * g];
        Edst.p[g] = (const int*)d_in[35 + 2 * g];
    }

    char* base = (char*)d_ws;
    size_t off = 0;
    auto alloc = [&](size_t bytes) -> void* {
        void* r = (void*)(base + off);
        off = (off + bytes + 255) & ~(size_t)255;
        return r;
    };
    // ---- persistent small region ----
    bf16* W12t_hi = (bf16*)alloc(128 * KP_HE * 2);  // memset block start
    bf16* W12t_lo = (bf16*)alloc(128 * KP_HE * 2);
    bf16* Btkv_hi = (bf16*)alloc(256 * E_DIM * 2);
    bf16* Btkv_lo = (bf16*)alloc(256 * E_DIM * 2);  // memset block end (245760 B)
    float* b12 = (float*)alloc(128 * 4);
    bf16* Wct_hi = (bf16*)alloc(256 * T_STRIDE * 2);
    bf16* Wct_lo = (bf16*)alloc(256 * T_STRIDE * 2);
    float* b_comp = (float*)alloc(256 * 4);
    bf16* Wm2t_hi = (bf16*)alloc(128 * 256 * 2);
    bf16* Wm2t_lo = (bf16*)alloc(128 * 256 * 2);
    float* q_t = (float*)alloc(N_NODES * Q_DIM * 4);
    int* bincnt = (int*)alloc(3 * NBIN * 4);
    int* binoff = (int*)alloc(3 * (NBIN + 1) * 4);
    int* bincursor = (int*)alloc(3 * NBIN * 4);
    int* rows = (int*)alloc(3 * (N_HE + 1) * 4);
    // ---- big buffers with lifetime overlays ----
    size_t T_start = off;
    bf16* T_hi = (bf16*)alloc((size_t)M_PAD * T_STRIDE * 2);   // [attn -> mlp1]
    bf16* T_lo = (bf16*)alloc((size_t)M_PAD * T_STRIDE * 2);
    size_t R_start = off;
    float* R = (float*)alloc((size_t)N_HE * R_STRIDE * 4);     // [R-gemm -> attn]
    int* ebuf = (int*)alloc((size_t)3 * E_EDGES * 4);          // [bin_csr -> attn]
    bf16* qhe_hi = (bf16*)alloc((size_t)M_PAD * E_DIM * 2);    // [q_he gemm -> R gemm]
    bf16* qhe_lo = (bf16*)alloc((size_t)M_PAD * E_DIM * 2);
    // overlays:
    bf16* he_hi = (bf16*)(base + T_start);                      // phase A only
    bf16* he_lo = he_hi + (size_t)M_PAD * KP_HE;
    unsigned* binbuf = (unsigned*)qhe_hi;                       // CSR staging, dead before q_he gemm
    bf16* h1_hi = (bf16*)(base + R_start);                      // mlp1 -> mlp2
    bf16* h1_lo = h1_hi + (size_t)M_PAD * 256;

    hipMemsetAsync(bincnt, 0, 3 * NBIN * 4, stream);
    hipMemsetAsync(W12t_hi, 0, 245760, stream); // zero-pads W12t + Btkv (hi & lo)

    // ---- binned CSR build ----
    {
        dim3 grid((E_EDGES + ECHUNK - 1) / ECHUNK, 3);
        coarse_hist3_kernel<<<grid, 256, 0, stream>>>(Esrc, bincnt);
        coarse_scan_kernel<<<1, 192, 0, stream>>>(bincnt, binoff, bincursor);
        bin_scatter_kernel<<<grid, 256, 0, stream>>>(Esrc, Edst, bincursor, binbuf);
        bin_csr_kernel<<<dim3(NBIN, 3), 256, 0, stream>>>(binbuf, binoff, rows, ebuf);
    }

    // ---- phase A: splits, weight prep, node q ----
    split_hefeat_kernel<<<(N_HE * KP_HE) / 256, 256, 0, stream>>>(he_feat, he_hi, he_lo);
    compose_w12_kernel<<<IN_F + 1, 256, 0, stream>>>(w1w, w1b, w2w, w2b, W12t_hi, W12t_lo, b12);
    prep_bkv_kernel<<<128, 256, 0, stream>>>(w6w_g[0], w6b_g[0], w6w_g[1], w6b_g[1],
                                             w6w_g[2], w6b_g[2], Btkv_hi, Btkv_lo);
    prep_wcomp_kernel<<<193, 256, 0, stream>>>(w7w_g[0], w7b_g[0], w7w_g[1], w7b_g[1],
                                               w7w_g[2], w7b_g[2], mlp1w, mlp1b, Wct_hi, Wct_lo, b_comp);
    prep_m2t_kernel<<<128, 256, 0, stream>>>(mlp2w, Wm2t_hi, Wm2t_lo);
    node_q_fused_kernel<<<N_NODES, 256, 0, stream>>>(Pq, q_t);

    const int MB = M_PAD / 128; // 391
    // q_he = he_feat @ W12 + b12 -> split [M_PAD][128]   (overwrites binbuf: dead)
    mfma_gemm_kernel<true, false, true><<<dim3(MB, 2), 256, 0, stream>>>(
        he_hi, he_lo, KP_HE, W12t_hi, W12t_lo, b12, nullptr, qhe_hi, qhe_lo, N_HE, E_DIM, E_DIM);
    // R = q_he @ B_kv -> f32 [N_HE][216]
    mfma_gemm_kernel<false, false, false><<<dim3(MB, 4), 256, 0, stream>>>(
        qhe_hi, qhe_lo, E_DIM, Btkv_hi, Btkv_lo, nullptr, R, nullptr, nullptr, N_HE, R_STRIDE, R_STRIDE);
    // attention -> T split [M_PAD][192]   (overwrites he: dead)
    attn_kernel<<<(3 * N_HE) / 4, 256, 0, stream>>>(R, q_t, rows, ebuf, T_hi, T_lo);
    // h1 = relu(T @ W_comp + b_comp) -> split [M_PAD][256]   (overwrites R/ebuf: dead)
    mfma_gemm_kernel<true, true, true><<<dim3(MB, 4), 256, 0, stream>>>(
        T_hi, T_lo, T_STRIDE, Wct_hi, Wct_lo, b_comp, nullptr, h1_hi, h1_lo, N_HE, 256, 256);
    // out = relu(h1 @ mlp2w + mlp2b) -> f32 [N_HE][128]
    mfma_gemm_kernel<true, true, false><<<dim3(MB, 2), 256, 0, stream>>>(
        h1_hi, h1_lo, 256, Wm2t_hi, Wm2t_lo, mlp2b, out, nullptr, nullptr, N_HE, E_DIM, E_DIM);
}